// Round 1
// baseline (525.279 us; speedup 1.0000x reference)
//
#include <hip/hip_runtime.h>
#include <math.h>

#define EPS 1e-6f
// B=2, C=256, N=32768 (32^3), g=8, heads=4, d=64

// ---------------- K0: weight prep ----------------
// W1[c][o] = q_w[o][c]*nq_w[c]  (K-major for coalesced chunk loads)
// W2[c][o] = proj_w[o][c]
// A[o] = sum_c q_w[o][c]*nq_w[c],  Bc[o] = sum_c q_w[o][c]*nq_b[c]
__global__ void prep_weights(const float* __restrict__ q_w,
                             const float* __restrict__ proj_w,
                             const float* __restrict__ nq_w,
                             const float* __restrict__ nq_b,
                             float* __restrict__ W1, float* __restrict__ W2,
                             float* __restrict__ A, float* __restrict__ Bc) {
    int o = blockIdx.x;   // 0..255
    int c = threadIdx.x;  // 0..255
    float qv = q_w[o * 256 + c];
    float w1 = qv * nq_w[c];
    W1[c * 256 + o] = w1;
    W2[c * 256 + o] = proj_w[o * 256 + c];
    float bcv = qv * nq_b[c];
    __shared__ float sA[4], sB[4];
    float a = w1, b = bcv;
    for (int off = 32; off > 0; off >>= 1) {
        a += __shfl_down(a, off);
        b += __shfl_down(b, off);
    }
    int wave = threadIdx.x >> 6, lane = threadIdx.x & 63;
    if (lane == 0) { sA[wave] = a; sB[wave] = b; }
    __syncthreads();
    if (threadIdx.x == 0) {
        A[o]  = sA[0] + sA[1] + sA[2] + sA[3];
        Bc[o] = sB[0] + sB[1] + sB[2] + sB[3];
    }
}

// ---------------- K1: adaptive avg pool 16^3 -> 2^3 ----------------
__global__ void pool_tokens(const float* __restrict__ x1, float* __restrict__ tokens) {
    int bc = blockIdx.x;  // b*256 + c, 512 blocks
    const float* base = x1 + (size_t)bc * 4096;
    int wave = threadIdx.x >> 6;     // 0..3, handles tokens 2w, 2w+1
    int lane = threadIdx.x & 63;
    int doff = lane >> 3, hoff = lane & 7;
    for (int t = wave * 2; t < wave * 2 + 2; ++t) {
        int gd = t >> 2, gh = (t >> 1) & 1, gw = t & 1;
        const float* p = base + (gd * 8 + doff) * 256 + (gh * 8 + hoff) * 16 + gw * 8;
        float4 v0 = *(const float4*)p;
        float4 v1 = *(const float4*)(p + 4);
        float s = v0.x + v0.y + v0.z + v0.w + v1.x + v1.y + v1.z + v1.w;
        for (int off = 32; off > 0; off >>= 1) s += __shfl_down(s, off);
        if (lane == 0) tokens[bc * 8 + t] = s * (1.0f / 512.0f);
    }
}

// ---------------- K2: dwconv + residual + LN + k/v projection ----------------
// kk[b][h][d][g], vv[b][h][g][d]
__global__ void tokens_kv(const float* __restrict__ tokens,
                          const float* __restrict__ dw_w,
                          const float* __restrict__ k_w,
                          const float* __restrict__ v_w,
                          const float* __restrict__ nkv_w,
                          const float* __restrict__ nkv_b,
                          float* __restrict__ kk, float* __restrict__ vv) {
    int b = blockIdx.x;
    int c = threadIdx.x;  // channel / output channel
    __shared__ float t2[256][8];
    __shared__ float u8[8], r8[8];
    float t[8];
    #pragma unroll
    for (int g = 0; g < 8; ++g) t[g] = tokens[(b * 256 + c) * 8 + g];
    float w[27];
    #pragma unroll
    for (int i = 0; i < 27; ++i) w[i] = dw_w[c * 27 + i];
    // depthwise 3x3x3 SAME on 2x2x2 grid, then residual
    #pragma unroll
    for (int z = 0; z < 2; ++z)
    #pragma unroll
    for (int y = 0; y < 2; ++y)
    #pragma unroll
    for (int x = 0; x < 2; ++x) {
        float s = 0.f;
        #pragma unroll
        for (int i = 0; i < 3; ++i) {
            int nz = z + i - 1; if (nz < 0 || nz > 1) continue;
            #pragma unroll
            for (int j = 0; j < 3; ++j) {
                int ny = y + j - 1; if (ny < 0 || ny > 1) continue;
                #pragma unroll
                for (int l = 0; l < 3; ++l) {
                    int nx = x + l - 1; if (nx < 0 || nx > 1) continue;
                    s += w[(i * 3 + j) * 3 + l] * t[nz * 4 + ny * 2 + nx];
                }
            }
        }
        int g = z * 4 + y * 2 + x;
        t2[c][g] = t[g] + s;
    }
    __syncthreads();
    if (c < 8) {
        float su = 0.f, sq = 0.f;
        for (int cc = 0; cc < 256; ++cc) { float v = t2[cc][c]; su += v; sq += v * v; }
        float u = su * (1.f / 256.f);
        float var = sq * (1.f / 256.f) - u * u;
        u8[c] = u;
        r8[c] = rsqrtf(var + EPS);
    }
    __syncthreads();
    int o = c;
    float acck[8] = {0,0,0,0,0,0,0,0}, accv[8] = {0,0,0,0,0,0,0,0};
    for (int cc = 0; cc < 256; ++cc) {
        float kwv = k_w[o * 256 + cc];
        float vwv = v_w[o * 256 + cc];
        float nw = nkv_w[cc], nb = nkv_b[cc];
        #pragma unroll
        for (int g = 0; g < 8; ++g) {
            float tv = t2[cc][g];
            float tn = nw * (tv - u8[g]) * r8[g] + nb;
            acck[g] += kwv * tn;
            accv[g] += vwv * tv;
        }
    }
    int h = o >> 6, d = o & 63;
    #pragma unroll
    for (int g = 0; g < 8; ++g) {
        kk[((b * 4 + h) * 64 + d) * 8 + g] = acck[g];
        vv[((b * 4 + h) * 8 + g) * 64 + d] = accv[g];
    }
}

// ---------------- K3: per-position LN stats of x2 ----------------
__global__ void ln_stats(const float* __restrict__ x2,
                         float* __restrict__ u, float* __restrict__ r) {
    int t = blockIdx.x * blockDim.x + threadIdx.x;  // 0..16383
    int n = t << 2;                                  // handles n..n+3
    int b = n >> 15;
    int pos = n & 32767;
    const float* p = x2 + (size_t)b * 8388608 + pos;
    float su0 = 0, su1 = 0, su2 = 0, su3 = 0;
    float sq0 = 0, sq1 = 0, sq2 = 0, sq3 = 0;
    for (int c = 0; c < 256; ++c) {
        float4 v = *(const float4*)(p + (size_t)c * 32768);
        su0 += v.x; sq0 += v.x * v.x;
        su1 += v.y; sq1 += v.y * v.y;
        su2 += v.z; sq2 += v.z * v.z;
        su3 += v.w; sq3 += v.w * v.w;
    }
    const float inv = 1.f / 256.f;
    float4 um, rm;
    um.x = su0 * inv; um.y = su1 * inv; um.z = su2 * inv; um.w = su3 * inv;
    rm.x = rsqrtf(sq0 * inv - um.x * um.x + EPS);
    rm.y = rsqrtf(sq1 * inv - um.y * um.y + EPS);
    rm.z = rsqrtf(sq2 * inv - um.z * um.z + EPS);
    rm.w = rsqrtf(sq3 * inv - um.w * um.w + EPS);
    *(float4*)(u + n) = um;
    *(float4*)(r + n) = rm;
}

// ---------------- K4: fused q-GEMM + attention + proj-GEMM ----------------
#define TN 64
#define KC 16
#define QP 68

__global__ __launch_bounds__(256, 1)
void fused_main(const float* __restrict__ x2,
                const float* __restrict__ W1,
                const float* __restrict__ W2,
                const float* __restrict__ Avec,
                const float* __restrict__ Bvec,
                const float* __restrict__ uarr,
                const float* __restrict__ rarr,
                const float* __restrict__ kk,
                const float* __restrict__ vv,
                float* __restrict__ out) {
    __shared__ __align__(16) float wsm[KC * 256];   // weight chunk [k][o]
    __shared__ __align__(16) float xs[KC][72];      // x chunk [k][n]
    __shared__ __align__(16) float qs[256][QP];     // q / attn-out [c][n]
    __shared__ __align__(16) float ks[4 * 64 * 8];  // k [h][d][g]
    __shared__ __align__(16) float vs[4 * 8 * 64];  // v [h][g][d]

    int tid = threadIdx.x;
    int n0g = blockIdx.x * TN;      // global position in [0, 65536)
    int b = n0g >> 15;
    int pos0 = n0g & 32767;
    const float* x2b = x2 + (size_t)b * 8388608 + pos0;

    // stage k/v for this batch (2048 floats each)
    {
        const float4* kkb = (const float4*)(kk + b * 2048);
        const float4* vvb = (const float4*)(vv + b * 2048);
        for (int i = tid; i < 512; i += 256) {
            ((float4*)ks)[i] = kkb[i];
            ((float4*)vs)[i] = vvb[i];
        }
    }

    int ty = tid >> 3;  // 0..31 -> o rows 8*ty..
    int tx = tid & 7;   // 0..7  -> n cols 8*tx..
    float acc[8][8];
    #pragma unroll
    for (int i = 0; i < 8; ++i)
        #pragma unroll
        for (int j = 0; j < 8; ++j) acc[i][j] = 0.f;

    // ---- GEMM1: q_pre = W1^T(K-major) * x2 ----
    for (int kc = 0; kc < 256; kc += KC) {
        __syncthreads();
        {   // W1 chunk: contiguous KC*256 floats
            const float4* src = (const float4*)(W1 + kc * 256);
            float4* dst = (float4*)wsm;
            #pragma unroll
            for (int i = 0; i < 4; ++i) dst[tid + 256 * i] = src[tid + 256 * i];
        }
        {   // x chunk
            int kr = tid >> 4;   // 0..15
            int j4 = tid & 15;   // 0..15
            float4 v = *(const float4*)(x2b + (size_t)(kc + kr) * 32768 + j4 * 4);
            *(float4*)&xs[kr][j4 * 4] = v;
        }
        __syncthreads();
        #pragma unroll
        for (int k = 0; k < KC; ++k) {
            float a[8], bb[8];
            *(float4*)&a[0]  = *(float4*)&wsm[k * 256 + 8 * ty];
            *(float4*)&a[4]  = *(float4*)&wsm[k * 256 + 8 * ty + 4];
            *(float4*)&bb[0] = *(float4*)&xs[k][8 * tx];
            *(float4*)&bb[4] = *(float4*)&xs[k][8 * tx + 4];
            #pragma unroll
            for (int i = 0; i < 8; ++i)
                #pragma unroll
                for (int j = 0; j < 8; ++j)
                    acc[i][j] += a[i] * bb[j];
        }
    }

    // ---- epilogue: LN correction, q -> LDS ----
    {
        float uv[8], rv[8], Ai[8], Bi[8];
        #pragma unroll
        for (int j = 0; j < 8; ++j) { uv[j] = uarr[n0g + 8 * tx + j]; rv[j] = rarr[n0g + 8 * tx + j]; }
        #pragma unroll
        for (int i = 0; i < 8; ++i) { Ai[i] = Avec[8 * ty + i]; Bi[i] = Bvec[8 * ty + i]; }
        #pragma unroll
        for (int i = 0; i < 8; ++i)
            #pragma unroll
            for (int j = 0; j < 8; ++j)
                qs[8 * ty + i][8 * tx + j] = rv[j] * (acc[i][j] - uv[j] * Ai[i]) + Bi[i];
    }
    __syncthreads();

    // ---- attention: one thread per (n, h); in-place q -> attn-out ----
    {
        int n = tid & 63;
        int h = tid >> 6;
        const float* ksh = ks + h * 512;  // [d][g]
        const float* vsh = vs + h * 512;  // [g][d]
        float logit[8];
        #pragma unroll
        for (int g = 0; g < 8; ++g) logit[g] = 0.f;
        for (int d = 0; d < 64; ++d) {
            float qv = qs[h * 64 + d][n];
            #pragma unroll
            for (int g = 0; g < 8; ++g) logit[g] += qv * ksh[d * 8 + g];
        }
        float m = logit[0];
        #pragma unroll
        for (int g = 1; g < 8; ++g) m = fmaxf(m, logit[g]);
        float p[8], s = 0.f;
        #pragma unroll
        for (int g = 0; g < 8; ++g) { p[g] = __expf((logit[g] - m) * 0.125f); s += p[g]; }
        float pinv = 1.f / s;
        #pragma unroll
        for (int g = 0; g < 8; ++g) p[g] *= pinv;
        for (int d = 0; d < 64; ++d) {
            float ov = 0.f;
            #pragma unroll
            for (int g = 0; g < 8; ++g) ov += p[g] * vsh[g * 64 + d];
            qs[h * 64 + d][n] = ov;  // safe: only this thread touches (h*64+d, n)
        }
    }

    // ---- GEMM2: final = W2^T(K-major) * attn_out ----
    float acc2[8][8];
    #pragma unroll
    for (int i = 0; i < 8; ++i)
        #pragma unroll
        for (int j = 0; j < 8; ++j) acc2[i][j] = 0.f;

    for (int kc = 0; kc < 256; kc += KC) {
        __syncthreads();
        {
            const float4* src = (const float4*)(W2 + kc * 256);
            float4* dst = (float4*)wsm;
            #pragma unroll
            for (int i = 0; i < 4; ++i) dst[tid + 256 * i] = src[tid + 256 * i];
        }
        __syncthreads();
        #pragma unroll
        for (int k = 0; k < KC; ++k) {
            float a[8], bb[8];
            *(float4*)&a[0]  = *(float4*)&wsm[k * 256 + 8 * ty];
            *(float4*)&a[4]  = *(float4*)&wsm[k * 256 + 8 * ty + 4];
            *(float4*)&bb[0] = *(float4*)&qs[kc + k][8 * tx];
            *(float4*)&bb[4] = *(float4*)&qs[kc + k][8 * tx + 4];
            #pragma unroll
            for (int i = 0; i < 8; ++i)
                #pragma unroll
                for (int j = 0; j < 8; ++j)
                    acc2[i][j] += a[i] * bb[j];
        }
    }

    // ---- store ----
    float* ob = out + (size_t)b * 8388608 + pos0;
    #pragma unroll
    for (int i = 0; i < 8; ++i) {
        float* row = ob + (size_t)(8 * ty + i) * 32768 + 8 * tx;
        *(float4*)row       = *(float4*)&acc2[i][0];
        *(float4*)(row + 4) = *(float4*)&acc2[i][4];
    }
}

extern "C" void kernel_launch(void* const* d_in, const int* in_sizes, int n_in,
                              void* d_out, int out_size, void* d_ws, size_t ws_size,
                              hipStream_t stream) {
    (void)in_sizes; (void)n_in; (void)out_size; (void)ws_size;
    const float* x2     = (const float*)d_in[0];
    const float* x1_low = (const float*)d_in[1];
    const float* q_w    = (const float*)d_in[2];
    const float* k_w    = (const float*)d_in[3];
    const float* v_w    = (const float*)d_in[4];
    const float* dw_w   = (const float*)d_in[5];
    const float* proj_w = (const float*)d_in[6];
    const float* nq_w   = (const float*)d_in[7];
    const float* nq_b   = (const float*)d_in[8];
    const float* nkv_w  = (const float*)d_in[9];
    const float* nkv_b  = (const float*)d_in[10];
    float* outp = (float*)d_out;

    float* wsf = (float*)d_ws;
    float* W1 = wsf;              // 65536
    float* W2 = wsf + 65536;      // 65536
    float* Av = wsf + 131072;     // 256
    float* Bv = wsf + 131328;     // 256
    float* u  = wsf + 131584;     // 65536
    float* r  = wsf + 197120;     // 65536
    float* tk = wsf + 262656;     // 4096
    float* kk = wsf + 266752;     // 4096
    float* vv = wsf + 270848;     // 4096

    prep_weights<<<256, 256, 0, stream>>>(q_w, proj_w, nq_w, nq_b, W1, W2, Av, Bv);
    pool_tokens<<<512, 256, 0, stream>>>(x1_low, tk);
    tokens_kv<<<2, 256, 0, stream>>>(tk, dw_w, k_w, v_w, nkv_w, nkv_b, kk, vv);
    ln_stats<<<64, 256, 0, stream>>>(x2, u, r);
    fused_main<<<1024, 256, 0, stream>>>(x2, W1, W2, Av, Bv, u, r, kk, vv, outp);
}

// Round 3
// 222.795 us; speedup vs baseline: 2.3577x; 2.3577x over previous
//
#include <hip/hip_runtime.h>
#include <math.h>

#define EPS 1e-6f
// B=2, C=256, N=32768 (32^3), g=8, heads=4, d=64

typedef __attribute__((ext_vector_type(8))) short bhalf8;
typedef __attribute__((ext_vector_type(4))) float floatx4;

__device__ __forceinline__ unsigned short f2bf(float f) {
    union { float f; unsigned u; } v; v.f = f;
    unsigned r = (v.u + 0x7fffu + ((v.u >> 16) & 1u)) >> 16;
    return (unsigned short)r;
}
__device__ __forceinline__ float bflo(unsigned u) {
    union { unsigned x; float f; } v; v.x = u << 16; return v.f;
}
__device__ __forceinline__ float bfhi(unsigned u) {
    union { unsigned x; float f; } v; v.x = u & 0xffff0000u; return v.f;
}
__device__ __forceinline__ void async16(const void* g, void* l) {
    __builtin_amdgcn_global_load_lds(
        (const __attribute__((address_space(1))) unsigned int*)g,
        (__attribute__((address_space(3))) unsigned int*)l, 16, 0, 0);
}

// ---------------- K0: weight prep ----------------
// fp32 (fallback): W1[c][o] = q_w[o][c]*nq_w[c], W2[c][o] = proj_w[o][c]
// bf16 (mfma): chunked [kc][o][32]: W1b[kc*8192 + o*32 + kk], kk = c&31, kc = c>>5
// A[o] = sum_c q_w[o][c]*nq_w[c],  Bc[o] = sum_c q_w[o][c]*nq_b[c]
__global__ void prep_weights(const float* __restrict__ q_w,
                             const float* __restrict__ proj_w,
                             const float* __restrict__ nq_w,
                             const float* __restrict__ nq_b,
                             float* __restrict__ W1, float* __restrict__ W2,
                             unsigned short* __restrict__ W1b,
                             unsigned short* __restrict__ W2b,
                             float* __restrict__ A, float* __restrict__ Bc) {
    int o = blockIdx.x;   // 0..255
    int c = threadIdx.x;  // 0..255
    float qv = q_w[o * 256 + c];
    float pv = proj_w[o * 256 + c];
    float w1 = qv * nq_w[c];
    W1[c * 256 + o] = w1;
    W2[c * 256 + o] = pv;
    int kc = c >> 5, kk = c & 31;
    W1b[kc * 8192 + o * 32 + kk] = f2bf(w1);
    W2b[kc * 8192 + o * 32 + kk] = f2bf(pv);
    float bcv = qv * nq_b[c];
    __shared__ float sA[4], sB[4];
    float a = w1, b = bcv;
    for (int off = 32; off > 0; off >>= 1) {
        a += __shfl_down(a, off);
        b += __shfl_down(b, off);
    }
    int wave = threadIdx.x >> 6, lane = threadIdx.x & 63;
    if (lane == 0) { sA[wave] = a; sB[wave] = b; }
    __syncthreads();
    if (threadIdx.x == 0) {
        A[o]  = sA[0] + sA[1] + sA[2] + sA[3];
        Bc[o] = sB[0] + sB[1] + sB[2] + sB[3];
    }
}

// ---------------- K1: adaptive avg pool 16^3 -> 2^3 ----------------
__global__ void pool_tokens(const float* __restrict__ x1, float* __restrict__ tokens) {
    int bc = blockIdx.x;  // b*256 + c, 512 blocks
    const float* base = x1 + (size_t)bc * 4096;
    int wave = threadIdx.x >> 6;
    int lane = threadIdx.x & 63;
    int doff = lane >> 3, hoff = lane & 7;
    for (int t = wave * 2; t < wave * 2 + 2; ++t) {
        int gd = t >> 2, gh = (t >> 1) & 1, gw = t & 1;
        const float* p = base + (gd * 8 + doff) * 256 + (gh * 8 + hoff) * 16 + gw * 8;
        float4 v0 = *(const float4*)p;
        float4 v1 = *(const float4*)(p + 4);
        float s = v0.x + v0.y + v0.z + v0.w + v1.x + v1.y + v1.z + v1.w;
        for (int off = 32; off > 0; off >>= 1) s += __shfl_down(s, off);
        if (lane == 0) tokens[bc * 8 + t] = s * (1.0f / 512.0f);
    }
}

// ---------------- K2: dwconv + residual + LN + k/v projection ----------------
// fp32: kk[b][h][d][g], vv[b][h][g][d]; kkb = bf16 copy of kk (same indexing!)
__global__ void tokens_kv(const float* __restrict__ tokens,
                          const float* __restrict__ dw_w,
                          const float* __restrict__ k_w,
                          const float* __restrict__ v_w,
                          const float* __restrict__ nkv_w,
                          const float* __restrict__ nkv_b,
                          float* __restrict__ kk, float* __restrict__ vv,
                          unsigned short* __restrict__ kkb) {
    int b = blockIdx.x;
    int c = threadIdx.x;
    __shared__ float t2[256][8];
    __shared__ float u8[8], r8[8];
    float t[8];
    #pragma unroll
    for (int g = 0; g < 8; ++g) t[g] = tokens[(b * 256 + c) * 8 + g];
    float w[27];
    #pragma unroll
    for (int i = 0; i < 27; ++i) w[i] = dw_w[c * 27 + i];
    #pragma unroll
    for (int z = 0; z < 2; ++z)
    #pragma unroll
    for (int y = 0; y < 2; ++y)
    #pragma unroll
    for (int x = 0; x < 2; ++x) {
        float s = 0.f;
        #pragma unroll
        for (int i = 0; i < 3; ++i) {
            int nz = z + i - 1; if (nz < 0 || nz > 1) continue;
            #pragma unroll
            for (int j = 0; j < 3; ++j) {
                int ny = y + j - 1; if (ny < 0 || ny > 1) continue;
                #pragma unroll
                for (int l = 0; l < 3; ++l) {
                    int nx = x + l - 1; if (nx < 0 || nx > 1) continue;
                    s += w[(i * 3 + j) * 3 + l] * t[nz * 4 + ny * 2 + nx];
                }
            }
        }
        int g = z * 4 + y * 2 + x;
        t2[c][g] = t[g] + s;
    }
    __syncthreads();
    if (c < 8) {
        float su = 0.f, sq = 0.f;
        for (int cc = 0; cc < 256; ++cc) { float v = t2[cc][c]; su += v; sq += v * v; }
        float u = su * (1.f / 256.f);
        float var = sq * (1.f / 256.f) - u * u;
        u8[c] = u;
        r8[c] = rsqrtf(var + EPS);
    }
    __syncthreads();
    int o = c;
    float acck[8] = {0,0,0,0,0,0,0,0}, accv[8] = {0,0,0,0,0,0,0,0};
    for (int cc = 0; cc < 256; ++cc) {
        float kwv = k_w[o * 256 + cc];
        float vwv = v_w[o * 256 + cc];
        float nw = nkv_w[cc], nb = nkv_b[cc];
        #pragma unroll
        for (int g = 0; g < 8; ++g) {
            float tv = t2[cc][g];
            float tn = nw * (tv - u8[g]) * r8[g] + nb;
            acck[g] += kwv * tn;
            accv[g] += vwv * tv;
        }
    }
    int h = o >> 6, d = o & 63;
    #pragma unroll
    for (int g = 0; g < 8; ++g) {
        int ki = ((b * 4 + h) * 64 + d) * 8 + g;   // = b*2048 + h*512 + d*8 + g
        int vi = ((b * 4 + h) * 8 + g) * 64 + d;   // = b*2048 + h*512 + g*64 + d
        kk[ki] = acck[g];
        vv[vi] = accv[g];
        kkb[ki] = f2bf(acck[g]);                    // FIXED: direct index
    }
}

// ---------------- K3a (fallback): per-position LN stats ----------------
__global__ void ln_stats(const float* __restrict__ x2,
                         float* __restrict__ u, float* __restrict__ r) {
    int t = blockIdx.x * blockDim.x + threadIdx.x;
    int n = t << 2;
    int b = n >> 15;
    int pos = n & 32767;
    const float* p = x2 + (size_t)b * 8388608 + pos;
    float su0 = 0, su1 = 0, su2 = 0, su3 = 0;
    float sq0 = 0, sq1 = 0, sq2 = 0, sq3 = 0;
    for (int c = 0; c < 256; ++c) {
        float4 v = *(const float4*)(p + (size_t)c * 32768);
        su0 += v.x; sq0 += v.x * v.x;
        su1 += v.y; sq1 += v.y * v.y;
        su2 += v.z; sq2 += v.z * v.z;
        su3 += v.w; sq3 += v.w * v.w;
    }
    const float inv = 1.f / 256.f;
    float4 um, rm;
    um.x = su0 * inv; um.y = su1 * inv; um.z = su2 * inv; um.w = su3 * inv;
    rm.x = rsqrtf(sq0 * inv - um.x * um.x + EPS);
    rm.y = rsqrtf(sq1 * inv - um.y * um.y + EPS);
    rm.z = rsqrtf(sq2 * inv - um.z * um.z + EPS);
    rm.w = rsqrtf(sq3 * inv - um.w * um.w + EPS);
    *(float4*)(u + n) = um;
    *(float4*)(r + n) = rm;
}

// ---------------- K3b (mfma path): LN stats + bf16 transpose x2 -> x2t ----------------
// x2t layout: row n (global, 0..65535) of 256 bf16, with 16B-groups swizzled:
//   element (n,c) stored at group (c>>3)^(n&7), offset c&7 within group.
__global__ __launch_bounds__(256) void xprep(const float* __restrict__ x2,
                                             unsigned short* __restrict__ x2t,
                                             float* __restrict__ u,
                                             float* __restrict__ r) {
    __shared__ unsigned short xt[64 * 256];   // swizzled bf16 tile, 32 KB
    __shared__ float part[16][64][2];         // 8 KB partial stats
    int t = threadIdx.x;
    int n4 = t & 15, cg = t >> 4;
    int n0g = blockIdx.x * 64;
    int b = n0g >> 15;
    int pos0 = n0g & 32767;
    const float* xb = x2 + (size_t)b * 8388608 + pos0 + n4 * 4;
    float su[4] = {0,0,0,0}, sq[4] = {0,0,0,0};
    for (int cc = 0; cc < 8; ++cc) {
        int p = cg + 16 * cc;       // c-pair index 0..127
        int c0 = 2 * p;
        float4 a = *(const float4*)(xb + (size_t)c0 * 32768);
        float4 bq = *(const float4*)(xb + (size_t)(c0 + 1) * 32768);
        float av[4] = {a.x, a.y, a.z, a.w};
        float bv[4] = {bq.x, bq.y, bq.z, bq.w};
        int gl = p >> 2, wsub = p & 3;
        #pragma unroll
        for (int i = 0; i < 4; ++i) {
            su[i] += av[i] + bv[i];
            sq[i] += av[i] * av[i] + bv[i] * bv[i];
            int row = 4 * n4 + i;
            unsigned val = (unsigned)f2bf(av[i]) | ((unsigned)f2bf(bv[i]) << 16);
            ((unsigned*)xt)[row * 128 + ((gl ^ (row & 7)) << 2) + wsub] = val;
        }
    }
    #pragma unroll
    for (int i = 0; i < 4; ++i) {
        part[cg][4 * n4 + i][0] = su[i];
        part[cg][4 * n4 + i][1] = sq[i];
    }
    __syncthreads();
    if (t < 64) {
        float S = 0, Q = 0;
        for (int g = 0; g < 16; ++g) { S += part[g][t][0]; Q += part[g][t][1]; }
        float mu = S * (1.f / 256.f);
        float rr = rsqrtf(Q * (1.f / 256.f) - mu * mu + EPS);
        u[n0g + t] = mu;
        r[n0g + t] = rr;
    }
    __syncthreads();
    // copy swizzled tile to global (identity layout; rotated order only)
    int row = t >> 2, qt = t & 3;
    unsigned short* dst = x2t + (size_t)(n0g + row) * 256 + qt * 64;
    const unsigned short* srow = xt + row * 256 + qt * 64;
    #pragma unroll
    for (int j = 0; j < 8; ++j) {
        int je = (j + row) & 7;
        *(uint4*)(dst + 8 * je) = *(const uint4*)(srow + 8 * je);
    }
}

// ---------------- K4b (mfma path): fused q-GEMM + attention + proj-GEMM ----------------
__global__ __launch_bounds__(256, 2)
void fused_mfma(const unsigned short* __restrict__ x2t,
                const unsigned short* __restrict__ W1b,
                const unsigned short* __restrict__ W2b,
                const float* __restrict__ Ag, const float* __restrict__ Bg,
                const float* __restrict__ ug, const float* __restrict__ rg,
                const unsigned short* __restrict__ kkb,
                const float* __restrict__ vvf,
                float* __restrict__ out) {
    __shared__ unsigned short XQ[16896];      // 33792 B: x tile [64][256], then q/attn [64][264]
    __shared__ unsigned short Wbf[2][8192];   // 2 x 16 KB weight chunk dbuf
    __shared__ unsigned short ks[2048];       // 4 KB: k bf16 [4][64][8]
    __shared__ float vs[2048];                // 8 KB: v fp32 [4][8][64]
    __shared__ float As[256], Bs[256], us[64], rs[64];

    const int tid = threadIdx.x;
    const int w = tid >> 6;
    const int lane = tid & 63;
    const int n0g = blockIdx.x * 64;
    const int b = n0g >> 15;

    // ---- stage: x tile (32 KB async), W1 chunk 0 (16 KB async), k/v, stats, A/B ----
    {
        const char* xg = (const char*)x2t + (size_t)n0g * 512;
        int base = w * 8192 + lane * 16;
        #pragma unroll
        for (int i = 0; i < 8; ++i)
            async16(xg + base + i * 1024, (char*)XQ + w * 8192 + i * 1024);
    }
    const char* w1g = (const char*)W1b;
    #pragma unroll
    for (int i = 0; i < 4; ++i)
        async16(w1g + w * 4096 + i * 1024 + lane * 16, (char*)Wbf[0] + w * 4096 + i * 1024);
    ((uint4*)ks)[tid] = ((const uint4*)(kkb + b * 2048))[tid];          // 4 KB
    ((float4*)vs)[tid]       = ((const float4*)(vvf + b * 2048))[tid];  // 8 KB in 2 steps
    ((float4*)vs)[256 + tid] = ((const float4*)(vvf + b * 2048))[256 + tid];
    if (tid < 64) { us[tid] = ug[n0g + tid]; rs[tid] = rg[n0g + tid]; }
    As[tid] = Ag[tid];
    Bs[tid] = Bg[tid];
    __syncthreads();

    const int m = lane & 15;
    const int qd = lane >> 4;

    floatx4 acc[4][4];
    #pragma unroll
    for (int i = 0; i < 4; ++i)
        #pragma unroll
        for (int j = 0; j < 4; ++j)
            acc[i][j] = (floatx4){0.f, 0.f, 0.f, 0.f};

    // ---- GEMM1: q_pre[o][n] = sum_c W1[o][c] * x[c][n] ----
    for (int kc = 0; kc < 8; ++kc) {
        if (kc < 7) {
            const char* wn = w1g + (kc + 1) * 16384;
            #pragma unroll
            for (int i = 0; i < 4; ++i)
                async16(wn + w * 4096 + i * 1024 + lane * 16,
                        (char*)Wbf[(kc + 1) & 1] + w * 4096 + i * 1024);
        }
        const unsigned short* wb = Wbf[kc & 1];
        bhalf8 af[4], bfr[4];
        #pragma unroll
        for (int t = 0; t < 4; ++t) {
            int o = (4 * w + t) * 16 + m;
            af[t] = *(const bhalf8*)(wb + o * 32 + qd * 8);
        }
        #pragma unroll
        for (int nt = 0; nt < 4; ++nt) {
            int n = nt * 16 + m;
            bfr[nt] = *(const bhalf8*)(XQ + n * 256 + (((4 * kc + qd) ^ (n & 7)) << 3));
        }
        #pragma unroll
        for (int t = 0; t < 4; ++t)
            #pragma unroll
            for (int nt = 0; nt < 4; ++nt)
                acc[t][nt] = __builtin_amdgcn_mfma_f32_16x16x32_bf16(af[t], bfr[nt], acc[t][nt], 0, 0, 0);
        __syncthreads();
    }

    // W2 chunk 0 prefetch (Wbf fully consumed; overlaps epilogue+attention)
    const char* w2g = (const char*)W2b;
    #pragma unroll
    for (int i = 0; i < 4; ++i)
        async16(w2g + w * 4096 + i * 1024 + lane * 16, (char*)Wbf[0] + w * 4096 + i * 1024);

    // ---- epilogue 1: LN correction, q -> XQ bf16 [n][264] ----
    #pragma unroll
    for (int t = 0; t < 4; ++t) {
        int ob = 64 * w + 16 * t + 4 * qd;
        floatx4 Af = *(const floatx4*)&As[ob];
        floatx4 Bf = *(const floatx4*)&Bs[ob];
        #pragma unroll
        for (int nt = 0; nt < 4; ++nt) {
            int n = nt * 16 + m;
            float uv = us[n], rv = rs[n];
            unsigned p0 = (unsigned)f2bf(rv * (acc[t][nt][0] - uv * Af[0]) + Bf[0])
                        | ((unsigned)f2bf(rv * (acc[t][nt][1] - uv * Af[1]) + Bf[1]) << 16);
            unsigned p1 = (unsigned)f2bf(rv * (acc[t][nt][2] - uv * Af[2]) + Bf[2])
                        | ((unsigned)f2bf(rv * (acc[t][nt][3] - uv * Af[3]) + Bf[3]) << 16);
            uint2 val; val.x = p0; val.y = p1;
            *(uint2*)(XQ + n * 264 + ob) = val;
        }
    }

    // ---- attention: thread (n=lane, h=w); reads/writes only its own wave's LDS cells ----
    {
        unsigned short* qrow = XQ + lane * 264 + w * 64;
        uint4 q4[8];
        #pragma unroll
        for (int j = 0; j < 8; ++j) q4[j] = *(const uint4*)(qrow + j * 8);
        float lg[8] = {0, 0, 0, 0, 0, 0, 0, 0};
        const unsigned short* kh = ks + w * 512;
        #pragma unroll
        for (int dp = 0; dp < 32; ++dp) {
            unsigned qq = ((const unsigned*)q4)[dp];
            float q0 = bflo(qq), q1 = bfhi(qq);
            uint4 k0 = *(const uint4*)(kh + dp * 16);
            uint4 k1 = *(const uint4*)(kh + dp * 16 + 8);
            lg[0] += q0 * bflo(k0.x); lg[1] += q0 * bfhi(k0.x);
            lg[2] += q0 * bflo(k0.y); lg[3] += q0 * bfhi(k0.y);
            lg[4] += q0 * bflo(k0.z); lg[5] += q0 * bfhi(k0.z);
            lg[6] += q0 * bflo(k0.w); lg[7] += q0 * bfhi(k0.w);
            lg[0] += q1 * bflo(k1.x); lg[1] += q1 * bfhi(k1.x);
            lg[2] += q1 * bflo(k1.y); lg[3] += q1 * bfhi(k1.y);
            lg[4] += q1 * bflo(k1.z); lg[5] += q1 * bfhi(k1.z);
            lg[6] += q1 * bflo(k1.w); lg[7] += q1 * bfhi(k1.w);
        }
        float mx = lg[0];
        #pragma unroll
        for (int g = 1; g < 8; ++g) mx = fmaxf(mx, lg[g]);
        float p[8], s = 0.f;
        #pragma unroll
        for (int g = 0; g < 8; ++g) { p[g] = __expf((lg[g] - mx) * 0.125f); s += p[g]; }
        float is = 1.f / s;
        #pragma unroll
        for (int g = 0; g < 8; ++g) p[g] *= is;
        float o2[64];
        #pragma unroll
        for (int j = 0; j < 64; ++j) o2[j] = 0.f;
        const float* vh = vs + w * 512;   // [g][64] fp32
        #pragma unroll
        for (int g = 0; g < 8; ++g) {
            float pg = p[g];
            #pragma unroll
            for (int j = 0; j < 16; ++j) {
                float4 vv4 = *(const float4*)(vh + g * 64 + j * 4);
                o2[4 * j + 0] += pg * vv4.x;
                o2[4 * j + 1] += pg * vv4.y;
                o2[4 * j + 2] += pg * vv4.z;
                o2[4 * j + 3] += pg * vv4.w;
            }
        }
        #pragma unroll
        for (int j = 0; j < 8; ++j) {
            uint4 pk;
            pk.x = (unsigned)f2bf(o2[8 * j + 0]) | ((unsigned)f2bf(o2[8 * j + 1]) << 16);
            pk.y = (unsigned)f2bf(o2[8 * j + 2]) | ((unsigned)f2bf(o2[8 * j + 3]) << 16);
            pk.z = (unsigned)f2bf(o2[8 * j + 4]) | ((unsigned)f2bf(o2[8 * j + 5]) << 16);
            pk.w = (unsigned)f2bf(o2[8 * j + 6]) | ((unsigned)f2bf(o2[8 * j + 7]) << 16);
            *(uint4*)(qrow + j * 8) = pk;
        }
    }
    __syncthreads();

    // ---- GEMM2: out[o][n] = sum_c W2[o][c] * attn[c][n] ----
    floatx4 acc2[4][4];
    #pragma unroll
    for (int i = 0; i < 4; ++i)
        #pragma unroll
        for (int j = 0; j < 4; ++j)
            acc2[i][j] = (floatx4){0.f, 0.f, 0.f, 0.f};

    for (int kc = 0; kc < 8; ++kc) {
        if (kc < 7) {
            const char* wn = w2g + (kc + 1) * 16384;
            #pragma unroll
            for (int i = 0; i < 4; ++i)
                async16(wn + w * 4096 + i * 1024 + lane * 16,
                        (char*)Wbf[(kc + 1) & 1] + w * 4096 + i * 1024);
        }
        const unsigned short* wb = Wbf[kc & 1];
        bhalf8 af[4], bfr[4];
        #pragma unroll
        for (int t = 0; t < 4; ++t) {
            int o = (4 * w + t) * 16 + m;
            af[t] = *(const bhalf8*)(wb + o * 32 + qd * 8);
        }
        #pragma unroll
        for (int nt = 0; nt < 4; ++nt) {
            int n = nt * 16 + m;
            bfr[nt] = *(const bhalf8*)(XQ + n * 264 + kc * 32 + qd * 8);
        }
        #pragma unroll
        for (int t = 0; t < 4; ++t)
            #pragma unroll
            for (int nt = 0; nt < 4; ++nt)
                acc2[t][nt] = __builtin_amdgcn_mfma_f32_16x16x32_bf16(af[t], bfr[nt], acc2[t][nt], 0, 0, 0);
        __syncthreads();
    }

    // ---- epilogue 2: store ----
    float* ob = out + (size_t)b * 8388608 + (n0g & 32767);
    #pragma unroll
    for (int t = 0; t < 4; ++t) {
        int o0 = 64 * w + 16 * t + 4 * qd;
        #pragma unroll
        for (int nt = 0; nt < 4; ++nt) {
            int n = nt * 16 + m;
            #pragma unroll
            for (int rr = 0; rr < 4; ++rr)
                ob[(size_t)(o0 + rr) * 32768 + n] = acc2[t][nt][rr];
        }
    }
}

// ---------------- K4a (fallback): fp32 fused (round-1 kernel) ----------------
#define TN 64
#define KC 16
#define QP 68

__global__ __launch_bounds__(256, 1)
void fused_main(const float* __restrict__ x2,
                const float* __restrict__ W1,
                const float* __restrict__ W2,
                const float* __restrict__ Avec,
                const float* __restrict__ Bvec,
                const float* __restrict__ uarr,
                const float* __restrict__ rarr,
                const float* __restrict__ kk,
                const float* __restrict__ vv,
                float* __restrict__ out) {
    __shared__ __align__(16) float wsm[KC * 256];
    __shared__ __align__(16) float xs[KC][72];
    __shared__ __align__(16) float qs[256][QP];
    __shared__ __align__(16) float ksm[4 * 64 * 8];
    __shared__ __align__(16) float vsm[4 * 8 * 64];

    int tid = threadIdx.x;
    int n0g = blockIdx.x * TN;
    int b = n0g >> 15;
    int pos0 = n0g & 32767;
    const float* x2b = x2 + (size_t)b * 8388608 + pos0;

    {
        const float4* kkb4 = (const float4*)(kk + b * 2048);
        const float4* vvb4 = (const float4*)(vv + b * 2048);
        for (int i = tid; i < 512; i += 256) {
            ((float4*)ksm)[i] = kkb4[i];
            ((float4*)vsm)[i] = vvb4[i];
        }
    }

    int ty = tid >> 3;
    int tx = tid & 7;
    float acc[8][8];
    #pragma unroll
    for (int i = 0; i < 8; ++i)
        #pragma unroll
        for (int j = 0; j < 8; ++j) acc[i][j] = 0.f;

    for (int kc = 0; kc < 256; kc += KC) {
        __syncthreads();
        {
            const float4* src = (const float4*)(W1 + kc * 256);
            float4* dst = (float4*)wsm;
            #pragma unroll
            for (int i = 0; i < 4; ++i) dst[tid + 256 * i] = src[tid + 256 * i];
        }
        {
            int kr = tid >> 4;
            int j4 = tid & 15;
            float4 v = *(const float4*)(x2b + (size_t)(kc + kr) * 32768 + j4 * 4);
            *(float4*)&xs[kr][j4 * 4] = v;
        }
        __syncthreads();
        #pragma unroll
        for (int k = 0; k < KC; ++k) {
            float a[8], bb[8];
            *(float4*)&a[0]  = *(float4*)&wsm[k * 256 + 8 * ty];
            *(float4*)&a[4]  = *(float4*)&wsm[k * 256 + 8 * ty + 4];
            *(float4*)&bb[0] = *(float4*)&xs[k][8 * tx];
            *(float4*)&bb[4] = *(float4*)&xs[k][8 * tx + 4];
            #pragma unroll
            for (int i = 0; i < 8; ++i)
                #pragma unroll
                for (int j = 0; j < 8; ++j)
                    acc[i][j] += a[i] * bb[j];
        }
    }

    {
        float uv[8], rv[8], Ai[8], Bi[8];
        #pragma unroll
        for (int j = 0; j < 8; ++j) { uv[j] = uarr[n0g + 8 * tx + j]; rv[j] = rarr[n0g + 8 * tx + j]; }
        #pragma unroll
        for (int i = 0; i < 8; ++i) { Ai[i] = Avec[8 * ty + i]; Bi[i] = Bvec[8 * ty + i]; }
        #pragma unroll
        for (int i = 0; i < 8; ++i)
            #pragma unroll
            for (int j = 0; j < 8; ++j)
                qs[8 * ty + i][8 * tx + j] = rv[j] * (acc[i][j] - uv[j] * Ai[i]) + Bi[i];
    }
    __syncthreads();

    {
        int n = tid & 63;
        int h = tid >> 6;
        const float* ksh = ksm + h * 512;
        const float* vsh = vsm + h * 512;
        float logit[8];
        #pragma unroll
        for (int g = 0; g < 8; ++g) logit[g] = 0.f;
        for (int d = 0; d < 64; ++d) {
            float qv = qs[h * 64 + d][n];
            #pragma unroll
            for (int g = 0; g < 8; ++g) logit[g] += qv * ksh[d * 8 + g];
        }
        float mm = logit[0];
        #pragma unroll
        for (int g = 1; g < 8; ++g) mm = fmaxf(mm, logit[g]);
        float p[8], s = 0.f;
        #pragma unroll
        for (int g = 0; g < 8; ++g) { p[g] = __expf((logit[g] - mm) * 0.125f); s += p[g]; }
        float pinv = 1.f / s;
        #pragma unroll
        for (int g = 0; g < 8; ++g) p[g] *= pinv;
        for (int d = 0; d < 64; ++d) {
            float ov = 0.f;
            #pragma unroll
            for (int g = 0; g < 8; ++g) ov += p[g] * vsh[g * 64 + d];
            qs[h * 64 + d][n] = ov;
        }
    }

    float acc2[8][8];
    #pragma unroll
    for (int i = 0; i < 8; ++i)
        #pragma unroll
        for (int j = 0; j < 8; ++j) acc2[i][j] = 0.f;

    for (int kc = 0; kc < 256; kc += KC) {
        __syncthreads();
        {
            const float4* src = (const float4*)(W2 + kc * 256);
            float4* dst = (float4*)wsm;
            #pragma unroll
            for (int i = 0; i < 4; ++i) dst[tid + 256 * i] = src[tid + 256 * i];
        }
        __syncthreads();
        #pragma unroll
        for (int k = 0; k < KC; ++k) {
            float a[8], bb[8];
            *(float4*)&a[0]  = *(float4*)&wsm[k * 256 + 8 * ty];
            *(float4*)&a[4]  = *(float4*)&wsm[k * 256 + 8 * ty + 4];
            *(float4*)&bb[0] = *(float4*)&qs[kc + k][8 * tx];
            *(float4*)&bb[4] = *(float4*)&qs[kc + k][8 * tx + 4];
            #pragma unroll
            for (int i = 0; i < 8; ++i)
                #pragma unroll
                for (int j = 0; j < 8; ++j)
                    acc2[i][j] += a[i] * bb[j];
        }
    }

    float* ob = out + (size_t)b * 8388608 + pos0;
    #pragma unroll
    for (int i = 0; i < 8; ++i) {
        float* row = ob + (size_t)(8 * ty + i) * 32768 + 8 * tx;
        *(float4*)row       = *(float4*)&acc2[i][0];
        *(float4*)(row + 4) = *(float4*)&acc2[i][4];
    }
}

extern "C" void kernel_launch(void* const* d_in, const int* in_sizes, int n_in,
                              void* d_out, int out_size, void* d_ws, size_t ws_size,
                              hipStream_t stream) {
    (void)in_sizes; (void)n_in; (void)out_size;
    const float* x2     = (const float*)d_in[0];
    const float* x1_low = (const float*)d_in[1];
    const float* q_w    = (const float*)d_in[2];
    const float* k_w    = (const float*)d_in[3];
    const float* v_w    = (const float*)d_in[4];
    const float* dw_w   = (const float*)d_in[5];
    const float* proj_w = (const float*)d_in[6];
    const float* nq_w   = (const float*)d_in[7];
    const float* nq_b   = (const float*)d_in[8];
    const float* nkv_w  = (const float*)d_in[9];
    const float* nkv_b  = (const float*)d_in[10];
    float* outp = (float*)d_out;

    float* wsf = (float*)d_ws;
    float* W1f = wsf;                         // 65536
    float* W2f = wsf + 65536;                 // 65536
    float* Av  = wsf + 131072;                // 256
    float* Bv  = wsf + 131328;                // 256
    float* u   = wsf + 131584;                // 65536
    float* r   = wsf + 197120;                // 65536
    float* tk  = wsf + 262656;                // 4096
    float* kkf = wsf + 266752;                // 4096
    float* vvf = wsf + 270848;                // 4096
    unsigned short* W1b = (unsigned short*)(wsf + 274944);   // 65536 ushorts (32768 f)
    unsigned short* W2b = (unsigned short*)(wsf + 307712);   // 65536 ushorts (32768 f)
    unsigned short* kkb = (unsigned short*)(wsf + 340480);   // 4096 ushorts (2048 f)
    unsigned short* x2t = (unsigned short*)(wsf + 342528);   // 16777216 ushorts
    const size_t need_bytes = (size_t)(342528 + 8388608) * 4;

    prep_weights<<<256, 256, 0, stream>>>(q_w, proj_w, nq_w, nq_b, W1f, W2f, W1b, W2b, Av, Bv);
    pool_tokens<<<512, 256, 0, stream>>>(x1_low, tk);
    tokens_kv<<<2, 256, 0, stream>>>(tk, dw_w, k_w, v_w, nkv_w, nkv_b, kkf, vvf, kkb);

    if (ws_size >= need_bytes) {
        xprep<<<1024, 256, 0, stream>>>(x2, x2t, u, r);
        fused_mfma<<<1024, 256, 0, stream>>>(x2t, W1b, W2b, Av, Bv, u, r, kkb, vvf, outp);
    } else {
        ln_stats<<<64, 256, 0, stream>>>(x2, u, r);
        fused_main<<<1024, 256, 0, stream>>>(x2, W1f, W2f, Av, Bv, u, r, kkf, vvf, outp);
    }
}

// Round 4
// 199.114 us; speedup vs baseline: 2.6381x; 1.1189x over previous
//
#include <hip/hip_runtime.h>
#include <math.h>

#define EPS 1e-6f
// B=2, C=256, N=32768 (32^3), g=8, heads=4, d=64

typedef __attribute__((ext_vector_type(8))) short bhalf8;
typedef __attribute__((ext_vector_type(4))) float floatx4;

__device__ __forceinline__ unsigned short f2bf(float f) {
    union { float f; unsigned u; } v; v.f = f;
    unsigned r = (v.u + 0x7fffu + ((v.u >> 16) & 1u)) >> 16;
    return (unsigned short)r;
}
__device__ __forceinline__ float bflo(unsigned u) {
    union { unsigned x; float f; } v; v.x = u << 16; return v.f;
}
__device__ __forceinline__ float bfhi(unsigned u) {
    union { unsigned x; float f; } v; v.x = u & 0xffff0000u; return v.f;
}

// ---------------- K0: weight prep ----------------
// fp32 (fallback): W1[c][o] = q_w[o][c]*nq_w[c], W2[c][o] = proj_w[o][c]
// bf16 (mfma): chunked [kc][o][32]: W1b[kc*8192 + o*32 + kk], kk = c&31, kc = c>>5
// A[o] = sum_c q_w[o][c]*nq_w[c],  Bc[o] = sum_c q_w[o][c]*nq_b[c]
__global__ void prep_weights(const float* __restrict__ q_w,
                             const float* __restrict__ proj_w,
                             const float* __restrict__ nq_w,
                             const float* __restrict__ nq_b,
                             float* __restrict__ W1, float* __restrict__ W2,
                             unsigned short* __restrict__ W1b,
                             unsigned short* __restrict__ W2b,
                             float* __restrict__ A, float* __restrict__ Bc) {
    int o = blockIdx.x;   // 0..255
    int c = threadIdx.x;  // 0..255
    float qv = q_w[o * 256 + c];
    float pv = proj_w[o * 256 + c];
    float w1 = qv * nq_w[c];
    W1[c * 256 + o] = w1;
    W2[c * 256 + o] = pv;
    int kc = c >> 5, kk = c & 31;
    W1b[kc * 8192 + o * 32 + kk] = f2bf(w1);
    W2b[kc * 8192 + o * 32 + kk] = f2bf(pv);
    float bcv = qv * nq_b[c];
    __shared__ float sA[4], sB[4];
    float a = w1, b = bcv;
    for (int off = 32; off > 0; off >>= 1) {
        a += __shfl_down(a, off);
        b += __shfl_down(b, off);
    }
    int wave = threadIdx.x >> 6, lane = threadIdx.x & 63;
    if (lane == 0) { sA[wave] = a; sB[wave] = b; }
    __syncthreads();
    if (threadIdx.x == 0) {
        A[o]  = sA[0] + sA[1] + sA[2] + sA[3];
        Bc[o] = sB[0] + sB[1] + sB[2] + sB[3];
    }
}

// ---------------- K1: adaptive avg pool 16^3 -> 2^3 ----------------
__global__ void pool_tokens(const float* __restrict__ x1, float* __restrict__ tokens) {
    int bc = blockIdx.x;  // b*256 + c, 512 blocks
    const float* base = x1 + (size_t)bc * 4096;
    int wave = threadIdx.x >> 6;
    int lane = threadIdx.x & 63;
    int doff = lane >> 3, hoff = lane & 7;
    for (int t = wave * 2; t < wave * 2 + 2; ++t) {
        int gd = t >> 2, gh = (t >> 1) & 1, gw = t & 1;
        const float* p = base + (gd * 8 + doff) * 256 + (gh * 8 + hoff) * 16 + gw * 8;
        float4 v0 = *(const float4*)p;
        float4 v1 = *(const float4*)(p + 4);
        float s = v0.x + v0.y + v0.z + v0.w + v1.x + v1.y + v1.z + v1.w;
        for (int off = 32; off > 0; off >>= 1) s += __shfl_down(s, off);
        if (lane == 0) tokens[bc * 8 + t] = s * (1.0f / 512.0f);
    }
}

// ---------------- K2: dwconv + residual + LN + k/v projection ----------------
// fp32: kk[b][h][d][g], vv[b][h][g][d]; kkb = bf16 copy of kk (same indexing)
__global__ void tokens_kv(const float* __restrict__ tokens,
                          const float* __restrict__ dw_w,
                          const float* __restrict__ k_w,
                          const float* __restrict__ v_w,
                          const float* __restrict__ nkv_w,
                          const float* __restrict__ nkv_b,
                          float* __restrict__ kk, float* __restrict__ vv,
                          unsigned short* __restrict__ kkb) {
    int b = blockIdx.x;
    int c = threadIdx.x;
    __shared__ float t2[256][8];
    __shared__ float u8[8], r8[8];
    float t[8];
    #pragma unroll
    for (int g = 0; g < 8; ++g) t[g] = tokens[(b * 256 + c) * 8 + g];
    float w[27];
    #pragma unroll
    for (int i = 0; i < 27; ++i) w[i] = dw_w[c * 27 + i];
    #pragma unroll
    for (int z = 0; z < 2; ++z)
    #pragma unroll
    for (int y = 0; y < 2; ++y)
    #pragma unroll
    for (int x = 0; x < 2; ++x) {
        float s = 0.f;
        #pragma unroll
        for (int i = 0; i < 3; ++i) {
            int nz = z + i - 1; if (nz < 0 || nz > 1) continue;
            #pragma unroll
            for (int j = 0; j < 3; ++j) {
                int ny = y + j - 1; if (ny < 0 || ny > 1) continue;
                #pragma unroll
                for (int l = 0; l < 3; ++l) {
                    int nx = x + l - 1; if (nx < 0 || nx > 1) continue;
                    s += w[(i * 3 + j) * 3 + l] * t[nz * 4 + ny * 2 + nx];
                }
            }
        }
        int g = z * 4 + y * 2 + x;
        t2[c][g] = t[g] + s;
    }
    __syncthreads();
    if (c < 8) {
        float su = 0.f, sq = 0.f;
        for (int cc = 0; cc < 256; ++cc) { float v = t2[cc][c]; su += v; sq += v * v; }
        float u = su * (1.f / 256.f);
        float var = sq * (1.f / 256.f) - u * u;
        u8[c] = u;
        r8[c] = rsqrtf(var + EPS);
    }
    __syncthreads();
    int o = c;
    float acck[8] = {0,0,0,0,0,0,0,0}, accv[8] = {0,0,0,0,0,0,0,0};
    for (int cc = 0; cc < 256; ++cc) {
        float kwv = k_w[o * 256 + cc];
        float vwv = v_w[o * 256 + cc];
        float nw = nkv_w[cc], nb = nkv_b[cc];
        #pragma unroll
        for (int g = 0; g < 8; ++g) {
            float tv = t2[cc][g];
            float tn = nw * (tv - u8[g]) * r8[g] + nb;
            acck[g] += kwv * tn;
            accv[g] += vwv * tv;
        }
    }
    int h = o >> 6, d = o & 63;
    #pragma unroll
    for (int g = 0; g < 8; ++g) {
        int ki = ((b * 4 + h) * 64 + d) * 8 + g;   // = b*2048 + h*512 + d*8 + g
        int vi = ((b * 4 + h) * 8 + g) * 64 + d;   // = b*2048 + h*512 + g*64 + d
        kk[ki] = acck[g];
        vv[vi] = accv[g];
        kkb[ki] = f2bf(acck[g]);
    }
}

// ---------------- K3a (fallback): per-position LN stats ----------------
__global__ void ln_stats(const float* __restrict__ x2,
                         float* __restrict__ u, float* __restrict__ r) {
    int t = blockIdx.x * blockDim.x + threadIdx.x;
    int n = t << 2;
    int b = n >> 15;
    int pos = n & 32767;
    const float* p = x2 + (size_t)b * 8388608 + pos;
    float su0 = 0, su1 = 0, su2 = 0, su3 = 0;
    float sq0 = 0, sq1 = 0, sq2 = 0, sq3 = 0;
    for (int c = 0; c < 256; ++c) {
        float4 v = *(const float4*)(p + (size_t)c * 32768);
        su0 += v.x; sq0 += v.x * v.x;
        su1 += v.y; sq1 += v.y * v.y;
        su2 += v.z; sq2 += v.z * v.z;
        su3 += v.w; sq3 += v.w * v.w;
    }
    const float inv = 1.f / 256.f;
    float4 um, rm;
    um.x = su0 * inv; um.y = su1 * inv; um.z = su2 * inv; um.w = su3 * inv;
    rm.x = rsqrtf(sq0 * inv - um.x * um.x + EPS);
    rm.y = rsqrtf(sq1 * inv - um.y * um.y + EPS);
    rm.z = rsqrtf(sq2 * inv - um.z * um.z + EPS);
    rm.w = rsqrtf(sq3 * inv - um.w * um.w + EPS);
    *(float4*)(u + n) = um;
    *(float4*)(r + n) = rm;
}

// ---------------- K4b (mfma path): fully fused ----------------
// Per block: 64 positions. Stage x fp32 -> stats + bf16 swizzled LDS tile.
// GEMM1 (reg-loaded W, no barriers) -> LN epilogue -> attention -> GEMM2 -> store.
// x-tile layout: ushort idx = n*256 + ((g ^ sw(n))<<3) + (c&7),
//   g = c>>3, sw(n) = ((n>>2)^n)&7 -- conflict-free for both the transpose
//   writes (spreads over n4) and the MFMA B-reads (spreads over m).
__global__ __launch_bounds__(256, 2)
void fused_mfma(const float* __restrict__ x2,
                const unsigned short* __restrict__ W1b,
                const unsigned short* __restrict__ W2b,
                const float* __restrict__ Ag, const float* __restrict__ Bg,
                const unsigned short* __restrict__ kkb,
                const float* __restrict__ vvf,
                float* __restrict__ out) {
    __shared__ unsigned short XQ[16896];      // 33792 B: x tile [64][256], then q/attn [64][264]
    __shared__ unsigned short ks[2048];       // 4 KB: k bf16 [4][64][8]
    __shared__ float vs[2048];                // 8 KB: v fp32 [4][8][64]
    __shared__ float part[16][64][2];         // 8 KB LN partial stats
    __shared__ float As[256], Bs[256], us[64], rs[64];

    const int tid = threadIdx.x;
    const int w = tid >> 6;
    const int lane = tid & 63;
    const int n0g = blockIdx.x * 64;
    const int b = n0g >> 15;

    // ---- stage k/v + A/B ----
    ((uint4*)ks)[tid] = ((const uint4*)(kkb + b * 2048))[tid];          // 4 KB
    ((float4*)vs)[tid]       = ((const float4*)(vvf + b * 2048))[tid];  // 8 KB
    ((float4*)vs)[256 + tid] = ((const float4*)(vvf + b * 2048))[256 + tid];
    As[tid] = Ag[tid];
    Bs[tid] = Bg[tid];

    // ---- stage 1: x fp32 -> stats + bf16 swizzled tile ----
    {
        const int n4 = tid & 15, cg = tid >> 4;
        const float* xb = x2 + (size_t)b * 8388608 + (n0g & 32767) + n4 * 4;
        float su[4] = {0,0,0,0}, sq[4] = {0,0,0,0};
        #pragma unroll
        for (int cc = 0; cc < 8; ++cc) {
            int p = cg + 16 * cc;   // c-pair 0..127
            int c0 = 2 * p;
            float4 a  = *(const float4*)(xb + (size_t)c0 * 32768);
            float4 bq = *(const float4*)(xb + (size_t)(c0 + 1) * 32768);
            int g = p >> 2, wsub = p & 3;
            float av[4] = {a.x, a.y, a.z, a.w};
            float bv[4] = {bq.x, bq.y, bq.z, bq.w};
            #pragma unroll
            for (int i = 0; i < 4; ++i) {
                su[i] += av[i] + bv[i];
                sq[i] += av[i] * av[i] + bv[i] * bv[i];
                int row = 4 * n4 + i;
                int swz = ((row >> 2) ^ row) & 7;
                unsigned val = (unsigned)f2bf(av[i]) | ((unsigned)f2bf(bv[i]) << 16);
                ((unsigned*)XQ)[row * 128 + ((g ^ swz) << 2) + wsub] = val;
            }
        }
        #pragma unroll
        for (int i = 0; i < 4; ++i) {
            part[cg][4 * n4 + i][0] = su[i];
            part[cg][4 * n4 + i][1] = sq[i];
        }
    }
    __syncthreads();
    if (tid < 64) {
        float S = 0, Q = 0;
        #pragma unroll
        for (int gg = 0; gg < 16; ++gg) { S += part[gg][tid][0]; Q += part[gg][tid][1]; }
        float mu = S * (1.f / 256.f);
        us[tid] = mu;
        rs[tid] = rsqrtf(Q * (1.f / 256.f) - mu * mu + EPS);
    }

    const int m = lane & 15;
    const int qd = lane >> 4;

    // ---- GEMM1: q_pre[o][n] = sum_c W1[o][c] * x[c][n]; W from global->VGPR ----
    floatx4 acc[4][4];
    #pragma unroll
    for (int i = 0; i < 4; ++i)
        #pragma unroll
        for (int j = 0; j < 4; ++j)
            acc[i][j] = (floatx4){0.f, 0.f, 0.f, 0.f};

    const unsigned short* w1p = W1b + (size_t)((4 * w) * 16 + m) * 32 + qd * 8;
    {
        bhalf8 afb[2][4];
        #pragma unroll
        for (int t = 0; t < 4; ++t) afb[0][t] = *(const bhalf8*)(w1p + t * 512);
        #pragma unroll
        for (int kc = 0; kc < 8; ++kc) {
            if (kc < 7) {
                #pragma unroll
                for (int t = 0; t < 4; ++t)
                    afb[(kc + 1) & 1][t] = *(const bhalf8*)(w1p + (kc + 1) * 8192 + t * 512);
            }
            bhalf8 bfr[4];
            #pragma unroll
            for (int nt = 0; nt < 4; ++nt) {
                int n = nt * 16 + m;
                int swz = ((n >> 2) ^ n) & 7;
                bfr[nt] = *(const bhalf8*)(XQ + n * 256 + (((4 * kc + qd) ^ swz) << 3));
            }
            #pragma unroll
            for (int t = 0; t < 4; ++t)
                #pragma unroll
                for (int nt = 0; nt < 4; ++nt)
                    acc[t][nt] = __builtin_amdgcn_mfma_f32_16x16x32_bf16(afb[kc & 1][t], bfr[nt], acc[t][nt], 0, 0, 0);
        }
    }
    __syncthreads();   // all waves done reading x-tile; us/rs ready

    // ---- epilogue 1: LN correction, q -> XQ bf16 [n][264] ----
    #pragma unroll
    for (int t = 0; t < 4; ++t) {
        int ob = 64 * w + 16 * t + 4 * qd;
        floatx4 Af = *(const floatx4*)&As[ob];
        floatx4 Bf = *(const floatx4*)&Bs[ob];
        #pragma unroll
        for (int nt = 0; nt < 4; ++nt) {
            int n = nt * 16 + m;
            float uv = us[n], rv = rs[n];
            unsigned p0 = (unsigned)f2bf(rv * (acc[t][nt][0] - uv * Af[0]) + Bf[0])
                        | ((unsigned)f2bf(rv * (acc[t][nt][1] - uv * Af[1]) + Bf[1]) << 16);
            unsigned p1 = (unsigned)f2bf(rv * (acc[t][nt][2] - uv * Af[2]) + Bf[2])
                        | ((unsigned)f2bf(rv * (acc[t][nt][3] - uv * Af[3]) + Bf[3]) << 16);
            uint2 val; val.x = p0; val.y = p1;
            *(uint2*)(XQ + n * 264 + ob) = val;
        }
    }

    // ---- attention: thread (n=lane, h=w); reads/writes only its own wave's LDS cells ----
    {
        unsigned short* qrow = XQ + lane * 264 + w * 64;
        uint4 q4[8];
        #pragma unroll
        for (int j = 0; j < 8; ++j) q4[j] = *(const uint4*)(qrow + j * 8);
        float lg[8] = {0, 0, 0, 0, 0, 0, 0, 0};
        const unsigned short* kh = ks + w * 512;
        #pragma unroll
        for (int dp = 0; dp < 32; ++dp) {
            unsigned qq = ((const unsigned*)q4)[dp];
            float q0 = bflo(qq), q1 = bfhi(qq);
            uint4 k0 = *(const uint4*)(kh + dp * 16);
            uint4 k1 = *(const uint4*)(kh + dp * 16 + 8);
            lg[0] += q0 * bflo(k0.x); lg[1] += q0 * bfhi(k0.x);
            lg[2] += q0 * bflo(k0.y); lg[3] += q0 * bfhi(k0.y);
            lg[4] += q0 * bflo(k0.z); lg[5] += q0 * bfhi(k0.z);
            lg[6] += q0 * bflo(k0.w); lg[7] += q0 * bfhi(k0.w);
            lg[0] += q1 * bflo(k1.x); lg[1] += q1 * bfhi(k1.x);
            lg[2] += q1 * bflo(k1.y); lg[3] += q1 * bfhi(k1.y);
            lg[4] += q1 * bflo(k1.z); lg[5] += q1 * bfhi(k1.z);
            lg[6] += q1 * bflo(k1.w); lg[7] += q1 * bfhi(k1.w);
        }
        float mx = lg[0];
        #pragma unroll
        for (int g = 1; g < 8; ++g) mx = fmaxf(mx, lg[g]);
        float p[8], s = 0.f;
        #pragma unroll
        for (int g = 0; g < 8; ++g) { p[g] = __expf((lg[g] - mx) * 0.125f); s += p[g]; }
        float is = 1.f / s;
        #pragma unroll
        for (int g = 0; g < 8; ++g) p[g] *= is;
        float o2[64];
        #pragma unroll
        for (int j = 0; j < 64; ++j) o2[j] = 0.f;
        const float* vh = vs + w * 512;   // [g][64] fp32
        #pragma unroll
        for (int g = 0; g < 8; ++g) {
            float pg = p[g];
            #pragma unroll
            for (int j = 0; j < 16; ++j) {
                float4 vv4 = *(const float4*)(vh + g * 64 + j * 4);
                o2[4 * j + 0] += pg * vv4.x;
                o2[4 * j + 1] += pg * vv4.y;
                o2[4 * j + 2] += pg * vv4.z;
                o2[4 * j + 3] += pg * vv4.w;
            }
        }
        #pragma unroll
        for (int j = 0; j < 8; ++j) {
            uint4 pk;
            pk.x = (unsigned)f2bf(o2[8 * j + 0]) | ((unsigned)f2bf(o2[8 * j + 1]) << 16);
            pk.y = (unsigned)f2bf(o2[8 * j + 2]) | ((unsigned)f2bf(o2[8 * j + 3]) << 16);
            pk.z = (unsigned)f2bf(o2[8 * j + 4]) | ((unsigned)f2bf(o2[8 * j + 5]) << 16);
            pk.w = (unsigned)f2bf(o2[8 * j + 6]) | ((unsigned)f2bf(o2[8 * j + 7]) << 16);
            *(uint4*)(qrow + j * 8) = pk;
        }
    }
    __syncthreads();

    // ---- GEMM2: out[o][n] = sum_c W2[o][c] * attn[c][n]; W from global->VGPR ----
    floatx4 acc2[4][4];
    #pragma unroll
    for (int i = 0; i < 4; ++i)
        #pragma unroll
        for (int j = 0; j < 4; ++j)
            acc2[i][j] = (floatx4){0.f, 0.f, 0.f, 0.f};

    const unsigned short* w2p = W2b + (size_t)((4 * w) * 16 + m) * 32 + qd * 8;
    {
        bhalf8 afb[2][4];
        #pragma unroll
        for (int t = 0; t < 4; ++t) afb[0][t] = *(const bhalf8*)(w2p + t * 512);
        #pragma unroll
        for (int kc = 0; kc < 8; ++kc) {
            if (kc < 7) {
                #pragma unroll
                for (int t = 0; t < 4; ++t)
                    afb[(kc + 1) & 1][t] = *(const bhalf8*)(w2p + (kc + 1) * 8192 + t * 512);
            }
            bhalf8 bfr[4];
            #pragma unroll
            for (int nt = 0; nt < 4; ++nt) {
                int n = nt * 16 + m;
                bfr[nt] = *(const bhalf8*)(XQ + n * 264 + kc * 32 + qd * 8);
            }
            #pragma unroll
            for (int t = 0; t < 4; ++t)
                #pragma unroll
                for (int nt = 0; nt < 4; ++nt)
                    acc2[t][nt] = __builtin_amdgcn_mfma_f32_16x16x32_bf16(afb[kc & 1][t], bfr[nt], acc2[t][nt], 0, 0, 0);
        }
    }

    // ---- store ----
    float* ob = out + (size_t)b * 8388608 + (n0g & 32767);
    #pragma unroll
    for (int t = 0; t < 4; ++t) {
        int o0 = 64 * w + 16 * t + 4 * qd;
        #pragma unroll
        for (int nt = 0; nt < 4; ++nt) {
            int n = nt * 16 + m;
            #pragma unroll
            for (int rr = 0; rr < 4; ++rr)
                ob[(size_t)(o0 + rr) * 32768 + n] = acc2[t][nt][rr];
        }
    }
}

// ---------------- K4a (fallback): fp32 fused (round-1 kernel) ----------------
#define TN 64
#define KC 16
#define QP 68

__global__ __launch_bounds__(256, 1)
void fused_main(const float* __restrict__ x2,
                const float* __restrict__ W1,
                const float* __restrict__ W2,
                const float* __restrict__ Avec,
                const float* __restrict__ Bvec,
                const float* __restrict__ uarr,
                const float* __restrict__ rarr,
                const float* __restrict__ kk,
                const float* __restrict__ vv,
                float* __restrict__ out) {
    __shared__ __align__(16) float wsm[KC * 256];
    __shared__ __align__(16) float xs[KC][72];
    __shared__ __align__(16) float qs[256][QP];
    __shared__ __align__(16) float ksm[4 * 64 * 8];
    __shared__ __align__(16) float vsm[4 * 8 * 64];

    int tid = threadIdx.x;
    int n0g = blockIdx.x * TN;
    int b = n0g >> 15;
    int pos0 = n0g & 32767;
    const float* x2b = x2 + (size_t)b * 8388608 + pos0;

    {
        const float4* kkb4 = (const float4*)(kk + b * 2048);
        const float4* vvb4 = (const float4*)(vv + b * 2048);
        for (int i = tid; i < 512; i += 256) {
            ((float4*)ksm)[i] = kkb4[i];
            ((float4*)vsm)[i] = vvb4[i];
        }
    }

    int ty = tid >> 3;
    int tx = tid & 7;
    float acc[8][8];
    #pragma unroll
    for (int i = 0; i < 8; ++i)
        #pragma unroll
        for (int j = 0; j < 8; ++j) acc[i][j] = 0.f;

    for (int kc = 0; kc < 256; kc += KC) {
        __syncthreads();
        {
            const float4* src = (const float4*)(W1 + kc * 256);
            float4* dst = (float4*)wsm;
            #pragma unroll
            for (int i = 0; i < 4; ++i) dst[tid + 256 * i] = src[tid + 256 * i];
        }
        {
            int kr = tid >> 4;
            int j4 = tid & 15;
            float4 v = *(const float4*)(x2b + (size_t)(kc + kr) * 32768 + j4 * 4);
            *(float4*)&xs[kr][j4 * 4] = v;
        }
        __syncthreads();
        #pragma unroll
        for (int k = 0; k < KC; ++k) {
            float a[8], bb[8];
            *(float4*)&a[0]  = *(float4*)&wsm[k * 256 + 8 * ty];
            *(float4*)&a[4]  = *(float4*)&wsm[k * 256 + 8 * ty + 4];
            *(float4*)&bb[0] = *(float4*)&xs[k][8 * tx];
            *(float4*)&bb[4] = *(float4*)&xs[k][8 * tx + 4];
            #pragma unroll
            for (int i = 0; i < 8; ++i)
                #pragma unroll
                for (int j = 0; j < 8; ++j)
                    acc[i][j] += a[i] * bb[j];
        }
    }

    {
        float uv[8], rv[8], Ai[8], Bi[8];
        #pragma unroll
        for (int j = 0; j < 8; ++j) { uv[j] = uarr[n0g + 8 * tx + j]; rv[j] = rarr[n0g + 8 * tx + j]; }
        #pragma unroll
        for (int i = 0; i < 8; ++i) { Ai[i] = Avec[8 * ty + i]; Bi[i] = Bvec[8 * ty + i]; }
        #pragma unroll
        for (int i = 0; i < 8; ++i)
            #pragma unroll
            for (int j = 0; j < 8; ++j)
                qs[8 * ty + i][8 * tx + j] = rv[j] * (acc[i][j] - uv[j] * Ai[i]) + Bi[i];
    }
    __syncthreads();

    {
        int n = tid & 63;
        int h = tid >> 6;
        const float* ksh = ksm + h * 512;
        const float* vsh = vsm + h * 512;
        float logit[8];
        #pragma unroll
        for (int g = 0; g < 8; ++g) logit[g] = 0.f;
        for (int d = 0; d < 64; ++d) {
            float qv = qs[h * 64 + d][n];
            #pragma unroll
            for (int g = 0; g < 8; ++g) logit[g] += qv * ksh[d * 8 + g];
        }
        float mm = logit[0];
        #pragma unroll
        for (int g = 1; g < 8; ++g) mm = fmaxf(mm, logit[g]);
        float p[8], s = 0.f;
        #pragma unroll
        for (int g = 0; g < 8; ++g) { p[g] = __expf((logit[g] - mm) * 0.125f); s += p[g]; }
        float pinv = 1.f / s;
        #pragma unroll
        for (int g = 0; g < 8; ++g) p[g] *= pinv;
        for (int d = 0; d < 64; ++d) {
            float ov = 0.f;
            #pragma unroll
            for (int g = 0; g < 8; ++g) ov += p[g] * vsh[g * 64 + d];
            qs[h * 64 + d][n] = ov;
        }
    }

    float acc2[8][8];
    #pragma unroll
    for (int i = 0; i < 8; ++i)
        #pragma unroll
        for (int j = 0; j < 8; ++j) acc2[i][j] = 0.f;

    for (int kc = 0; kc < 256; kc += KC) {
        __syncthreads();
        {
            const float4* src = (const float4*)(W2 + kc * 256);
            float4* dst = (float4*)wsm;
            #pragma unroll
            for (int i = 0; i < 4; ++i) dst[tid + 256 * i] = src[tid + 256 * i];
        }
        __syncthreads();
        #pragma unroll
        for (int k = 0; k < KC; ++k) {
            float a[8], bb[8];
            *(float4*)&a[0]  = *(float4*)&wsm[k * 256 + 8 * ty];
            *(float4*)&a[4]  = *(float4*)&wsm[k * 256 + 8 * ty + 4];
            *(float4*)&bb[0] = *(float4*)&qs[kc + k][8 * tx];
            *(float4*)&bb[4] = *(float4*)&qs[kc + k][8 * tx + 4];
            #pragma unroll
            for (int i = 0; i < 8; ++i)
                #pragma unroll
                for (int j = 0; j < 8; ++j)
                    acc2[i][j] += a[i] * bb[j];
        }
    }

    float* ob = out + (size_t)b * 8388608 + pos0;
    #pragma unroll
    for (int i = 0; i < 8; ++i) {
        float* row = ob + (size_t)(8 * ty + i) * 32768 + 8 * tx;
        *(float4*)row       = *(float4*)&acc2[i][0];
        *(float4*)(row + 4) = *(float4*)&acc2[i][4];
    }
}

extern "C" void kernel_launch(void* const* d_in, const int* in_sizes, int n_in,
                              void* d_out, int out_size, void* d_ws, size_t ws_size,
                              hipStream_t stream) {
    (void)in_sizes; (void)n_in; (void)out_size;
    const float* x2     = (const float*)d_in[0];
    const float* x1_low = (const float*)d_in[1];
    const float* q_w    = (const float*)d_in[2];
    const float* k_w    = (const float*)d_in[3];
    const float* v_w    = (const float*)d_in[4];
    const float* dw_w   = (const float*)d_in[5];
    const float* proj_w = (const float*)d_in[6];
    const float* nq_w   = (const float*)d_in[7];
    const float* nq_b   = (const float*)d_in[8];
    const float* nkv_w  = (const float*)d_in[9];
    const float* nkv_b  = (const float*)d_in[10];
    float* outp = (float*)d_out;

    float* wsf = (float*)d_ws;
    float* W1f = wsf;                         // 65536
    float* W2f = wsf + 65536;                 // 65536
    float* Av  = wsf + 131072;                // 256
    float* Bv  = wsf + 131328;                // 256
    float* u   = wsf + 131584;                // 65536 (fallback only)
    float* r   = wsf + 197120;                // 65536 (fallback only)
    float* tk  = wsf + 262656;                // 4096
    float* kkf = wsf + 266752;                // 4096
    float* vvf = wsf + 270848;                // 4096
    unsigned short* W1b = (unsigned short*)(wsf + 274944);   // 65536 ushorts (32768 f)
    unsigned short* W2b = (unsigned short*)(wsf + 307712);   // 65536 ushorts (32768 f)
    unsigned short* kkb = (unsigned short*)(wsf + 340480);   // 4096 ushorts (1024 f)
    const size_t need_bytes = (size_t)341504 * 4;

    prep_weights<<<256, 256, 0, stream>>>(q_w, proj_w, nq_w, nq_b, W1f, W2f, W1b, W2b, Av, Bv);
    pool_tokens<<<512, 256, 0, stream>>>(x1_low, tk);
    tokens_kv<<<2, 256, 0, stream>>>(tk, dw_w, k_w, v_w, nkv_w, nkv_b, kkf, vvf, kkb);

    if (ws_size >= need_bytes) {
        fused_mfma<<<1024, 256, 0, stream>>>(x2, W1b, W2b, Av, Bv, kkb, vvf, outp);
    } else {
        ln_stats<<<64, 256, 0, stream>>>(x2, u, r);
        fused_main<<<1024, 256, 0, stream>>>(x2, W1f, W2f, Av, Bv, u, r, kkf, vvf, outp);
    }
}

// Round 5
// 190.678 us; speedup vs baseline: 2.7548x; 1.0442x over previous
//
#include <hip/hip_runtime.h>
#include <math.h>

#define EPS 1e-6f
// B=2, C=256, N=32768 (32^3), g=8, heads=4, d=64

typedef __attribute__((ext_vector_type(8))) short bhalf8;
typedef __attribute__((ext_vector_type(4))) float floatx4;

__device__ __forceinline__ unsigned short f2bf(float f) {
    union { float f; unsigned u; } v; v.f = f;
    unsigned r = (v.u + 0x7fffu + ((v.u >> 16) & 1u)) >> 16;
    return (unsigned short)r;
}
__device__ __forceinline__ float bflo(unsigned u) {
    union { unsigned x; float f; } v; v.x = u << 16; return v.f;
}
__device__ __forceinline__ float bfhi(unsigned u) {
    union { unsigned x; float f; } v; v.x = u & 0xffff0000u; return v.f;
}

// ---------------- K_pre1: weight prep (blocks 0..255) + avg-pool (blocks 256..767) ----------------
// W1[c][o] = q_w[o][c]*nq_w[c] (fp32 fallback), W2[c][o] = proj_w[o][c]
// bf16: chunked [kc][o][32]: W1b[kc*8192 + o*32 + (c&31)], kc = c>>5
// A[o] = sum_c q_w[o][c]*nq_w[c],  Bc[o] = sum_c q_w[o][c]*nq_b[c]
__global__ void pre1(const float* __restrict__ q_w,
                     const float* __restrict__ proj_w,
                     const float* __restrict__ nq_w,
                     const float* __restrict__ nq_b,
                     float* __restrict__ W1, float* __restrict__ W2,
                     unsigned short* __restrict__ W1b,
                     unsigned short* __restrict__ W2b,
                     float* __restrict__ A, float* __restrict__ Bc,
                     const float* __restrict__ x1, float* __restrict__ tokens) {
    if (blockIdx.x < 256) {
        int o = blockIdx.x;
        int c = threadIdx.x;
        float qv = q_w[o * 256 + c];
        float pv = proj_w[o * 256 + c];
        float w1 = qv * nq_w[c];
        W1[c * 256 + o] = w1;
        W2[c * 256 + o] = pv;
        int kc = c >> 5, kk = c & 31;
        W1b[kc * 8192 + o * 32 + kk] = f2bf(w1);
        W2b[kc * 8192 + o * 32 + kk] = f2bf(pv);
        float bcv = qv * nq_b[c];
        __shared__ float sA[4], sB[4];
        float a = w1, b = bcv;
        for (int off = 32; off > 0; off >>= 1) {
            a += __shfl_down(a, off);
            b += __shfl_down(b, off);
        }
        int wave = threadIdx.x >> 6, lane = threadIdx.x & 63;
        if (lane == 0) { sA[wave] = a; sB[wave] = b; }
        __syncthreads();
        if (threadIdx.x == 0) {
            A[o]  = sA[0] + sA[1] + sA[2] + sA[3];
            Bc[o] = sB[0] + sB[1] + sB[2] + sB[3];
        }
    } else {
        int bc = blockIdx.x - 256;  // b*256 + c
        const float* base = x1 + (size_t)bc * 4096;
        int wave = threadIdx.x >> 6;
        int lane = threadIdx.x & 63;
        int doff = lane >> 3, hoff = lane & 7;
        for (int t = wave * 2; t < wave * 2 + 2; ++t) {
            int gd = t >> 2, gh = (t >> 1) & 1, gw = t & 1;
            const float* p = base + (gd * 8 + doff) * 256 + (gh * 8 + hoff) * 16 + gw * 8;
            float4 v0 = *(const float4*)p;
            float4 v1 = *(const float4*)(p + 4);
            float s = v0.x + v0.y + v0.z + v0.w + v1.x + v1.y + v1.z + v1.w;
            for (int off = 32; off > 0; off >>= 1) s += __shfl_down(s, off);
            if (lane == 0) tokens[bc * 8 + t] = s * (1.0f / 512.0f);
        }
    }
}

// ---------------- K_pre2: dwconv + residual + LN -> t2g (raw), tng (normalized) ----------------
__global__ void tokens_prep(const float* __restrict__ tokens,
                            const float* __restrict__ dw_w,
                            const float* __restrict__ nkv_w,
                            const float* __restrict__ nkv_b,
                            float* __restrict__ t2g, float* __restrict__ tng) {
    int b = blockIdx.x;
    int c = threadIdx.x;
    __shared__ float t2[256][8];
    __shared__ float u8[8], r8[8];
    float t[8];
    #pragma unroll
    for (int g = 0; g < 8; ++g) t[g] = tokens[(b * 256 + c) * 8 + g];
    float w[27];
    #pragma unroll
    for (int i = 0; i < 27; ++i) w[i] = dw_w[c * 27 + i];
    #pragma unroll
    for (int z = 0; z < 2; ++z)
    #pragma unroll
    for (int y = 0; y < 2; ++y)
    #pragma unroll
    for (int x = 0; x < 2; ++x) {
        float s = 0.f;
        #pragma unroll
        for (int i = 0; i < 3; ++i) {
            int nz = z + i - 1; if (nz < 0 || nz > 1) continue;
            #pragma unroll
            for (int j = 0; j < 3; ++j) {
                int ny = y + j - 1; if (ny < 0 || ny > 1) continue;
                #pragma unroll
                for (int l = 0; l < 3; ++l) {
                    int nx = x + l - 1; if (nx < 0 || nx > 1) continue;
                    s += w[(i * 3 + j) * 3 + l] * t[nz * 4 + ny * 2 + nx];
                }
            }
        }
        int g = z * 4 + y * 2 + x;
        t2[c][g] = t[g] + s;
    }
    __syncthreads();
    if (c < 8) {
        float su = 0.f, sq = 0.f;
        for (int cc = 0; cc < 256; ++cc) { float v = t2[cc][c]; su += v; sq += v * v; }
        float u = su * (1.f / 256.f);
        float var = sq * (1.f / 256.f) - u * u;
        u8[c] = u;
        r8[c] = rsqrtf(var + EPS);
    }
    __syncthreads();
    float nw = nkv_w[c], nb = nkv_b[c];
    #pragma unroll
    for (int g = 0; g < 8; ++g) {
        float tv = t2[c][g];
        t2g[(b * 256 + c) * 8 + g] = tv;
        tng[(b * 256 + c) * 8 + g] = nw * (tv - u8[g]) * r8[g] + nb;
    }
}

// ---------------- K_pre3: k/v projections, one wave per output channel ----------------
// kk[b][h][d][g] fp32 + bf16 copy kkb ; vv[b][h][g][d] fp32
__global__ void tokens_proj(const float* __restrict__ k_w,
                            const float* __restrict__ v_w,
                            const float* __restrict__ t2g,
                            const float* __restrict__ tng,
                            float* __restrict__ kk, float* __restrict__ vv,
                            unsigned short* __restrict__ kkb) {
    int b = blockIdx.x >> 6;
    int og = blockIdx.x & 63;
    int w = threadIdx.x >> 6;
    int lane = threadIdx.x & 63;
    int o = og * 4 + w;
    float acck[8] = {0,0,0,0,0,0,0,0}, accv[8] = {0,0,0,0,0,0,0,0};
    #pragma unroll
    for (int i = 0; i < 4; ++i) {
        int c = lane + 64 * i;
        float kw = k_w[o * 256 + c];
        float vw = v_w[o * 256 + c];
        const float* tb = t2g + (size_t)(b * 256 + c) * 8;
        const float* nb = tng + (size_t)(b * 256 + c) * 8;
        float4 ta0 = *(const float4*)tb;
        float4 ta1 = *(const float4*)(tb + 4);
        float4 tn0 = *(const float4*)nb;
        float4 tn1 = *(const float4*)(nb + 4);
        acck[0] += kw * tn0.x; acck[1] += kw * tn0.y; acck[2] += kw * tn0.z; acck[3] += kw * tn0.w;
        acck[4] += kw * tn1.x; acck[5] += kw * tn1.y; acck[6] += kw * tn1.z; acck[7] += kw * tn1.w;
        accv[0] += vw * ta0.x; accv[1] += vw * ta0.y; accv[2] += vw * ta0.z; accv[3] += vw * ta0.w;
        accv[4] += vw * ta1.x; accv[5] += vw * ta1.y; accv[6] += vw * ta1.z; accv[7] += vw * ta1.w;
    }
    #pragma unroll
    for (int g = 0; g < 8; ++g)
        for (int off = 32; off > 0; off >>= 1) {
            acck[g] += __shfl_down(acck[g], off);
            accv[g] += __shfl_down(accv[g], off);
        }
    if (lane == 0) {
        #pragma unroll
        for (int g = 0; g < 8; ++g) {
            int ki = b * 2048 + o * 8 + g;
            int vi = b * 2048 + (o >> 6) * 512 + g * 64 + (o & 63);
            kk[ki] = acck[g];
            kkb[ki] = f2bf(acck[g]);
            vv[vi] = accv[g];
        }
    }
}

// ---------------- K_pre3a (fallback): per-position LN stats ----------------
__global__ void ln_stats(const float* __restrict__ x2,
                         float* __restrict__ u, float* __restrict__ r) {
    int t = blockIdx.x * blockDim.x + threadIdx.x;
    int n = t << 2;
    int b = n >> 15;
    int pos = n & 32767;
    const float* p = x2 + (size_t)b * 8388608 + pos;
    float su0 = 0, su1 = 0, su2 = 0, su3 = 0;
    float sq0 = 0, sq1 = 0, sq2 = 0, sq3 = 0;
    for (int c = 0; c < 256; ++c) {
        float4 v = *(const float4*)(p + (size_t)c * 32768);
        su0 += v.x; sq0 += v.x * v.x;
        su1 += v.y; sq1 += v.y * v.y;
        su2 += v.z; sq2 += v.z * v.z;
        su3 += v.w; sq3 += v.w * v.w;
    }
    const float inv = 1.f / 256.f;
    float4 um, rm;
    um.x = su0 * inv; um.y = su1 * inv; um.z = su2 * inv; um.w = su3 * inv;
    rm.x = rsqrtf(sq0 * inv - um.x * um.x + EPS);
    rm.y = rsqrtf(sq1 * inv - um.y * um.y + EPS);
    rm.z = rsqrtf(sq2 * inv - um.z * um.z + EPS);
    rm.w = rsqrtf(sq3 * inv - um.w * um.w + EPS);
    *(float4*)(u + n) = um;
    *(float4*)(r + n) = rm;
}

// ---------------- K4: fully fused (mfma path) ----------------
// Per block: 64 positions. Stage x fp32 -> stats + bf16 swizzled LDS tile.
// GEMM1 (reg W, no inner barriers) -> LN epilogue -> attention -> GEMM2 -> store.
// Tile layout (x AND q, both swizzled-256): ushort idx = n*256 + ((gl ^ sw(n))<<3) + (c&7),
//   gl = c>>3, sw(n) = ((n>>2)^n)&7. Bank-uniform for staging writes, MFMA B-reads
//   (b128), epilogue writes, attention reads/writes.
// LDS: XQ 32768 + KVP 12288 (part[16][64][2] aliased with ks 4KB + vs 8KB) + 2560
//   = 47616 B -> 3 blocks/CU.
__global__ __launch_bounds__(256, 3)
void fused_mfma(const float* __restrict__ x2,
                const unsigned short* __restrict__ W1b,
                const unsigned short* __restrict__ W2b,
                const float* __restrict__ Ag, const float* __restrict__ Bg,
                const unsigned short* __restrict__ kkb,
                const float* __restrict__ vvf,
                float* __restrict__ out) {
    __shared__ __align__(16) unsigned short XQ[16384];   // 32768 B
    __shared__ __align__(16) float KVP[3072];            // 12288 B: part, then ks|vs
    __shared__ float As[256], Bs[256], us[64], rs[64];

    const int tid = threadIdx.x;
    const int w = tid >> 6;
    const int lane = tid & 63;
    const int n0g = blockIdx.x * 64;
    const int b = n0g >> 15;

    // early k/v global->reg (LDS region still holds LN partials)
    uint4  kreg  = ((const uint4*)(kkb + b * 2048))[tid];
    float4 vreg0 = ((const float4*)(vvf + b * 2048))[tid];
    float4 vreg1 = ((const float4*)(vvf + b * 2048))[256 + tid];
    As[tid] = Ag[tid];
    Bs[tid] = Bg[tid];

    // ---- stage: x fp32 -> stats partials + bf16 swizzled tile ----
    {
        const int n4 = tid & 15, cg = tid >> 4;
        const float* xb = x2 + (size_t)b * 8388608 + (n0g & 32767) + n4 * 4;
        float su[4] = {0,0,0,0}, sq[4] = {0,0,0,0};
        #pragma unroll
        for (int cc = 0; cc < 8; ++cc) {
            int p = cg + 16 * cc;   // c-pair 0..127
            int c0 = 2 * p;
            float4 a  = *(const float4*)(xb + (size_t)c0 * 32768);
            float4 bq = *(const float4*)(xb + (size_t)(c0 + 1) * 32768);
            int g = p >> 2, wsub = p & 3;
            float av[4] = {a.x, a.y, a.z, a.w};
            float bv[4] = {bq.x, bq.y, bq.z, bq.w};
            #pragma unroll
            for (int i = 0; i < 4; ++i) {
                su[i] += av[i] + bv[i];
                sq[i] += av[i] * av[i] + bv[i] * bv[i];
                int row = 4 * n4 + i;
                int swz = ((row >> 2) ^ row) & 7;
                unsigned val = (unsigned)f2bf(av[i]) | ((unsigned)f2bf(bv[i]) << 16);
                ((unsigned*)XQ)[row * 128 + ((g ^ swz) << 2) + wsub] = val;
            }
        }
        #pragma unroll
        for (int i = 0; i < 4; ++i) {
            KVP[cg * 128 + (4 * n4 + i) * 2]     = su[i];
            KVP[cg * 128 + (4 * n4 + i) * 2 + 1] = sq[i];
        }
    }
    __syncthreads();   // B1: tile + partials visible
    if (tid < 64) {
        float S = 0, Q = 0;
        #pragma unroll
        for (int gg = 0; gg < 16; ++gg) { S += KVP[gg * 128 + tid * 2]; Q += KVP[gg * 128 + tid * 2 + 1]; }
        float mu = S * (1.f / 256.f);
        us[tid] = mu;
        rs[tid] = rsqrtf(Q * (1.f / 256.f) - mu * mu + EPS);
    }
    __syncthreads();   // B2: partials consumed -> region reusable for k/v
    unsigned short* ks = (unsigned short*)KVP;   // 4096 B: k bf16 [4][64][8]
    float* vs = KVP + 1024;                      // 8192 B: v fp32 [4][8][64]
    ((uint4*)ks)[tid] = kreg;
    ((float4*)vs)[tid] = vreg0;
    ((float4*)vs)[256 + tid] = vreg1;

    const int m = lane & 15;
    const int qd = lane >> 4;

    // ---- GEMM1: q_pre[o][n] = sum_c W1[o][c] * x[c][n]; W global->VGPR, no barriers ----
    floatx4 acc[4][4];
    #pragma unroll
    for (int i = 0; i < 4; ++i)
        #pragma unroll
        for (int j = 0; j < 4; ++j)
            acc[i][j] = (floatx4){0.f, 0.f, 0.f, 0.f};

    const unsigned short* w1p = W1b + (size_t)((4 * w) * 16 + m) * 32 + qd * 8;
    {
        bhalf8 afb[2][4];
        #pragma unroll
        for (int t = 0; t < 4; ++t) afb[0][t] = *(const bhalf8*)(w1p + t * 512);
        #pragma unroll
        for (int kc = 0; kc < 8; ++kc) {
            if (kc < 7) {
                #pragma unroll
                for (int t = 0; t < 4; ++t)
                    afb[(kc + 1) & 1][t] = *(const bhalf8*)(w1p + (kc + 1) * 8192 + t * 512);
            }
            bhalf8 bfr[4];
            #pragma unroll
            for (int nt = 0; nt < 4; ++nt) {
                int n = nt * 16 + m;
                int swz = ((n >> 2) ^ n) & 7;
                bfr[nt] = *(const bhalf8*)(XQ + n * 256 + (((4 * kc + qd) ^ swz) << 3));
            }
            #pragma unroll
            for (int t = 0; t < 4; ++t)
                #pragma unroll
                for (int nt = 0; nt < 4; ++nt)
                    acc[t][nt] = __builtin_amdgcn_mfma_f32_16x16x32_bf16(afb[kc & 1][t], bfr[nt], acc[t][nt], 0, 0, 0);
        }
    }
    __syncthreads();   // B3: x-tile free; ks/vs visible; us/rs ready

    // ---- epilogue 1: LN correction, q -> XQ (swizzled-256, bf16) ----
    #pragma unroll
    for (int t = 0; t < 4; ++t) {
        int ob = 64 * w + 16 * t + 4 * qd;
        floatx4 Af = *(const floatx4*)&As[ob];
        floatx4 Bf = *(const floatx4*)&Bs[ob];
        int gq = ob >> 3, off = ob & 7;
        #pragma unroll
        for (int nt = 0; nt < 4; ++nt) {
            int n = nt * 16 + m;
            int swz = ((n >> 2) ^ n) & 7;
            float uv = us[n], rv = rs[n];
            unsigned p0 = (unsigned)f2bf(rv * (acc[t][nt][0] - uv * Af[0]) + Bf[0])
                        | ((unsigned)f2bf(rv * (acc[t][nt][1] - uv * Af[1]) + Bf[1]) << 16);
            unsigned p1 = (unsigned)f2bf(rv * (acc[t][nt][2] - uv * Af[2]) + Bf[2])
                        | ((unsigned)f2bf(rv * (acc[t][nt][3] - uv * Af[3]) + Bf[3]) << 16);
            uint2 val; val.x = p0; val.y = p1;
            *(uint2*)(XQ + n * 256 + ((gq ^ swz) << 3) + off) = val;
        }
    }

    // ---- attention: thread (n=lane, h=w); logical c-group gl -> physical gl^sw(n) ----
    {
        const int sw = ((lane >> 2) ^ lane) & 7;
        unsigned short* qrow = XQ + lane * 256;
        uint4 q4[8];
        #pragma unroll
        for (int gl = 0; gl < 8; ++gl)
            q4[gl] = *(const uint4*)(qrow + ((8 * w + (gl ^ sw)) << 3));
        // note: q4[gl] holds logical c = 64w+8gl..+7? No: physical group 8w+(gl^sw)
        // stores logical group 8w+gl only when XOR'd; recover ordering:
        // element at logical group L is stored at physical L^sw -> read physical
        // P=8w+(gl^sw) returns logical 8w+gl. So q4[gl] IS logical group gl. OK.
        float lg[8] = {0, 0, 0, 0, 0, 0, 0, 0};
        const unsigned short* kh = ks + w * 512;
        #pragma unroll
        for (int dp = 0; dp < 32; ++dp) {
            unsigned qq = ((const unsigned*)q4)[dp];
            float q0 = bflo(qq), q1 = bfhi(qq);
            uint4 k0 = *(const uint4*)(kh + dp * 16);
            uint4 k1 = *(const uint4*)(kh + dp * 16 + 8);
            lg[0] += q0 * bflo(k0.x); lg[1] += q0 * bfhi(k0.x);
            lg[2] += q0 * bflo(k0.y); lg[3] += q0 * bfhi(k0.y);
            lg[4] += q0 * bflo(k0.z); lg[5] += q0 * bfhi(k0.z);
            lg[6] += q0 * bflo(k0.w); lg[7] += q0 * bfhi(k0.w);
            lg[0] += q1 * bflo(k1.x); lg[1] += q1 * bfhi(k1.x);
            lg[2] += q1 * bflo(k1.y); lg[3] += q1 * bfhi(k1.y);
            lg[4] += q1 * bflo(k1.z); lg[5] += q1 * bfhi(k1.z);
            lg[6] += q1 * bflo(k1.w); lg[7] += q1 * bfhi(k1.w);
        }
        float mx = lg[0];
        #pragma unroll
        for (int g = 1; g < 8; ++g) mx = fmaxf(mx, lg[g]);
        float p[8], s = 0.f;
        #pragma unroll
        for (int g = 0; g < 8; ++g) { p[g] = __expf((lg[g] - mx) * 0.125f); s += p[g]; }
        float is = 1.f / s;
        #pragma unroll
        for (int g = 0; g < 8; ++g) p[g] *= is;
        float o2[64];
        #pragma unroll
        for (int j = 0; j < 64; ++j) o2[j] = 0.f;
        const float* vh = vs + w * 512;   // [g][64] fp32
        #pragma unroll
        for (int g = 0; g < 8; ++g) {
            float pg = p[g];
            #pragma unroll
            for (int j = 0; j < 16; ++j) {
                float4 vv4 = *(const float4*)(vh + g * 64 + j * 4);
                o2[4 * j + 0] += pg * vv4.x;
                o2[4 * j + 1] += pg * vv4.y;
                o2[4 * j + 2] += pg * vv4.z;
                o2[4 * j + 3] += pg * vv4.w;
            }
        }
        #pragma unroll
        for (int gl = 0; gl < 8; ++gl) {
            uint4 pk;
            pk.x = (unsigned)f2bf(o2[8 * gl + 0]) | ((unsigned)f2bf(o2[8 * gl + 1]) << 16);
            pk.y = (unsigned)f2bf(o2[8 * gl + 2]) | ((unsigned)f2bf(o2[8 * gl + 3]) << 16);
            pk.z = (unsigned)f2bf(o2[8 * gl + 4]) | ((unsigned)f2bf(o2[8 * gl + 5]) << 16);
            pk.w = (unsigned)f2bf(o2[8 * gl + 6]) | ((unsigned)f2bf(o2[8 * gl + 7]) << 16);
            *(uint4*)(qrow + ((8 * w + (gl ^ sw)) << 3)) = pk;
        }
    }
    __syncthreads();   // B4

    // ---- GEMM2: out[o][n] = sum_c W2[o][c] * attn[c][n] ----
    floatx4 acc2[4][4];
    #pragma unroll
    for (int i = 0; i < 4; ++i)
        #pragma unroll
        for (int j = 0; j < 4; ++j)
            acc2[i][j] = (floatx4){0.f, 0.f, 0.f, 0.f};

    const unsigned short* w2p = W2b + (size_t)((4 * w) * 16 + m) * 32 + qd * 8;
    {
        bhalf8 afb[2][4];
        #pragma unroll
        for (int t = 0; t < 4; ++t) afb[0][t] = *(const bhalf8*)(w2p + t * 512);
        #pragma unroll
        for (int kc = 0; kc < 8; ++kc) {
            if (kc < 7) {
                #pragma unroll
                for (int t = 0; t < 4; ++t)
                    afb[(kc + 1) & 1][t] = *(const bhalf8*)(w2p + (kc + 1) * 8192 + t * 512);
            }
            bhalf8 bfr[4];
            #pragma unroll
            for (int nt = 0; nt < 4; ++nt) {
                int n = nt * 16 + m;
                int swz = ((n >> 2) ^ n) & 7;
                bfr[nt] = *(const bhalf8*)(XQ + n * 256 + (((4 * kc + qd) ^ swz) << 3));
            }
            #pragma unroll
            for (int t = 0; t < 4; ++t)
                #pragma unroll
                for (int nt = 0; nt < 4; ++nt)
                    acc2[t][nt] = __builtin_amdgcn_mfma_f32_16x16x32_bf16(afb[kc & 1][t], bfr[nt], acc2[t][nt], 0, 0, 0);
        }
    }

    // ---- store ----
    float* ob = out + (size_t)b * 8388608 + (n0g & 32767);
    #pragma unroll
    for (int t = 0; t < 4; ++t) {
        int o0 = 64 * w + 16 * t + 4 * qd;
        #pragma unroll
        for (int nt = 0; nt < 4; ++nt) {
            int n = nt * 16 + m;
            #pragma unroll
            for (int rr = 0; rr < 4; ++rr)
                ob[(size_t)(o0 + rr) * 32768 + n] = acc2[t][nt][rr];
        }
    }
}

// ---------------- fallback: fp32 fused (round-1 kernel) ----------------
#define TN 64
#define KC 16
#define QP 68

__global__ __launch_bounds__(256, 1)
void fused_main(const float* __restrict__ x2,
                const float* __restrict__ W1,
                const float* __restrict__ W2,
                const float* __restrict__ Avec,
                const float* __restrict__ Bvec,
                const float* __restrict__ uarr,
                const float* __restrict__ rarr,
                const float* __restrict__ kk,
                const float* __restrict__ vv,
                float* __restrict__ out) {
    __shared__ __align__(16) float wsm[KC * 256];
    __shared__ __align__(16) float xs[KC][72];
    __shared__ __align__(16) float qs[256][QP];
    __shared__ __align__(16) float ksm[4 * 64 * 8];
    __shared__ __align__(16) float vsm[4 * 8 * 64];

    int tid = threadIdx.x;
    int n0g = blockIdx.x * TN;
    int b = n0g >> 15;
    int pos0 = n0g & 32767;
    const float* x2b = x2 + (size_t)b * 8388608 + pos0;

    {
        const float4* kkb4 = (const float4*)(kk + b * 2048);
        const float4* vvb4 = (const float4*)(vv + b * 2048);
        for (int i = tid; i < 512; i += 256) {
            ((float4*)ksm)[i] = kkb4[i];
            ((float4*)vsm)[i] = vvb4[i];
        }
    }

    int ty = tid >> 3;
    int tx = tid & 7;
    float acc[8][8];
    #pragma unroll
    for (int i = 0; i < 8; ++i)
        #pragma unroll
        for (int j = 0; j < 8; ++j) acc[i][j] = 0.f;

    for (int kc = 0; kc < 256; kc += KC) {
        __syncthreads();
        {
            const float4* src = (const float4*)(W1 + kc * 256);
            float4* dst = (float4*)wsm;
            #pragma unroll
            for (int i = 0; i < 4; ++i) dst[tid + 256 * i] = src[tid + 256 * i];
        }
        {
            int kr = tid >> 4;
            int j4 = tid & 15;
            float4 v = *(const float4*)(x2b + (size_t)(kc + kr) * 32768 + j4 * 4);
            *(float4*)&xs[kr][j4 * 4] = v;
        }
        __syncthreads();
        #pragma unroll
        for (int k = 0; k < KC; ++k) {
            float a[8], bb[8];
            *(float4*)&a[0]  = *(float4*)&wsm[k * 256 + 8 * ty];
            *(float4*)&a[4]  = *(float4*)&wsm[k * 256 + 8 * ty + 4];
            *(float4*)&bb[0] = *(float4*)&xs[k][8 * tx];
            *(float4*)&bb[4] = *(float4*)&xs[k][8 * tx + 4];
            #pragma unroll
            for (int i = 0; i < 8; ++i)
                #pragma unroll
                for (int j = 0; j < 8; ++j)
                    acc[i][j] += a[i] * bb[j];
        }
    }

    {
        float uv[8], rv[8], Ai[8], Bi[8];
        #pragma unroll
        for (int j = 0; j < 8; ++j) { uv[j] = uarr[n0g + 8 * tx + j]; rv[j] = rarr[n0g + 8 * tx + j]; }
        #pragma unroll
        for (int i = 0; i < 8; ++i) { Ai[i] = Avec[8 * ty + i]; Bi[i] = Bvec[8 * ty + i]; }
        #pragma unroll
        for (int i = 0; i < 8; ++i)
            #pragma unroll
            for (int j = 0; j < 8; ++j)
                qs[8 * ty + i][8 * tx + j] = rv[j] * (acc[i][j] - uv[j] * Ai[i]) + Bi[i];
    }
    __syncthreads();

    {
        int n = tid & 63;
        int h = tid >> 6;
        const float* ksh = ksm + h * 512;
        const float* vsh = vsm + h * 512;
        float logit[8];
        #pragma unroll
        for (int g = 0; g < 8; ++g) logit[g] = 0.f;
        for (int d = 0; d < 64; ++d) {
            float qv = qs[h * 64 + d][n];
            #pragma unroll
            for (int g = 0; g < 8; ++g) logit[g] += qv * ksh[d * 8 + g];
        }
        float mm = logit[0];
        #pragma unroll
        for (int g = 1; g < 8; ++g) mm = fmaxf(mm, logit[g]);
        float p[8], s = 0.f;
        #pragma unroll
        for (int g = 0; g < 8; ++g) { p[g] = __expf((logit[g] - mm) * 0.125f); s += p[g]; }
        float pinv = 1.f / s;
        #pragma unroll
        for (int g = 0; g < 8; ++g) p[g] *= pinv;
        for (int d = 0; d < 64; ++d) {
            float ov = 0.f;
            #pragma unroll
            for (int g = 0; g < 8; ++g) ov += p[g] * vsh[g * 64 + d];
            qs[h * 64 + d][n] = ov;
        }
    }

    float acc2[8][8];
    #pragma unroll
    for (int i = 0; i < 8; ++i)
        #pragma unroll
        for (int j = 0; j < 8; ++j) acc2[i][j] = 0.f;

    for (int kc = 0; kc < 256; kc += KC) {
        __syncthreads();
        {
            const float4* src = (const float4*)(W2 + kc * 256);
            float4* dst = (float4*)wsm;
            #pragma unroll
            for (int i = 0; i < 4; ++i) dst[tid + 256 * i] = src[tid + 256 * i];
        }
        __syncthreads();
        #pragma unroll
        for (int k = 0; k < KC; ++k) {
            float a[8], bb[8];
            *(float4*)&a[0]  = *(float4*)&wsm[k * 256 + 8 * ty];
            *(float4*)&a[4]  = *(float4*)&wsm[k * 256 + 8 * ty + 4];
            *(float4*)&bb[0] = *(float4*)&qs[kc + k][8 * tx];
            *(float4*)&bb[4] = *(float4*)&qs[kc + k][8 * tx + 4];
            #pragma unroll
            for (int i = 0; i < 8; ++i)
                #pragma unroll
                for (int j = 0; j < 8; ++j)
                    acc2[i][j] += a[i] * bb[j];
        }
    }

    float* ob = out + (size_t)b * 8388608 + pos0;
    #pragma unroll
    for (int i = 0; i < 8; ++i) {
        float* row = ob + (size_t)(8 * ty + i) * 32768 + 8 * tx;
        *(float4*)row       = *(float4*)&acc2[i][0];
        *(float4*)(row + 4) = *(float4*)&acc2[i][4];
    }
}

extern "C" void kernel_launch(void* const* d_in, const int* in_sizes, int n_in,
                              void* d_out, int out_size, void* d_ws, size_t ws_size,
                              hipStream_t stream) {
    (void)in_sizes; (void)n_in; (void)out_size;
    const float* x2     = (const float*)d_in[0];
    const float* x1_low = (const float*)d_in[1];
    const float* q_w    = (const float*)d_in[2];
    const float* k_w    = (const float*)d_in[3];
    const float* v_w    = (const float*)d_in[4];
    const float* dw_w   = (const float*)d_in[5];
    const float* proj_w = (const float*)d_in[6];
    const float* nq_w   = (const float*)d_in[7];
    const float* nq_b   = (const float*)d_in[8];
    const float* nkv_w  = (const float*)d_in[9];
    const float* nkv_b  = (const float*)d_in[10];
    float* outp = (float*)d_out;

    float* wsf = (float*)d_ws;
    float* W1f = wsf;                         // 65536
    float* W2f = wsf + 65536;                 // 65536
    float* Av  = wsf + 131072;                // 256
    float* Bv  = wsf + 131328;                // 256
    float* u   = wsf + 131584;                // 65536 (fallback only)
    float* r   = wsf + 197120;                // 65536 (fallback only)
    float* tk  = wsf + 262656;                // 4096
    float* kkf = wsf + 266752;                // 4096
    float* vvf = wsf + 270848;                // 4096
    unsigned short* W1b = (unsigned short*)(wsf + 274944);   // 65536 ushorts
    unsigned short* W2b = (unsigned short*)(wsf + 307712);   // 65536 ushorts
    unsigned short* kkb = (unsigned short*)(wsf + 340480);   // 4096 ushorts
    float* t2g = wsf + 342528;                // 4096
    float* tng = wsf + 346624;                // 4096
    const size_t need_bytes = (size_t)350720 * 4;

    pre1<<<768, 256, 0, stream>>>(q_w, proj_w, nq_w, nq_b, W1f, W2f, W1b, W2b, Av, Bv,
                                  x1_low, tk);
    tokens_prep<<<2, 256, 0, stream>>>(tk, dw_w, nkv_w, nkv_b, t2g, tng);
    tokens_proj<<<128, 256, 0, stream>>>(k_w, v_w, t2g, tng, kkf, vvf, kkb);

    if (ws_size >= need_bytes) {
        fused_mfma<<<1024, 256, 0, stream>>>(x2, W1b, W2b, Av, Bv, kkb, vvf, outp);
    } else {
        ln_stats<<<64, 256, 0, stream>>>(x2, u, r);
        fused_main<<<1024, 256, 0, stream>>>(x2, W1f, W2f, Av, Bv, u, r, kkf, vvf, outp);
    }
}